// Round 1
// baseline (4273.367 us; speedup 1.0000x reference)
//
#include <hip/hip_runtime.h>
#include <hip/hip_bf16.h>

// MultiGAT on MI355X — round 0 baseline (all fp32, vector ALU).
//
// Math restructuring vs reference (exact up to fp reassociation):
//  - MASK_FILL = -1e-8  =>  exp(-1e-8) == 1.0f exactly in fp32. So softmax over
//    scores where masked entries ~ weight 1:
//       active q:  numer[d] = S_all[d] + sum_{active k} (exp(tanh(sq_q+sk_k))-1) * qk[k,d]
//                  denom    = 2048 + sum_{active k} (exp(tanh(..))-1)
//       masked q:  all scores equal -> uniform attn -> hid = tanh(S_all/2048)
//    where S_all[d] = sum over ALL k of qk[k,h,d].
//  - Output uses only row N-1 after layer 2, so layer-2 attention is 1 q-row.
//
// Workspace layout (floats), total ~204 MB:
//   feat1[16][2048][768], qk[16][2048][768], sq/sk[16][2048][6],
//   S_part[16][8][768], S_all[16][768], hidU[16][768], gout[16][768],
//   actList/inactList[4][2048] (int), counts[8] (int)

#define BB 4
#define NP 2047
#define NN 2048
#define DD 768
#define HH 6
#define DHH 128
#define FHH 768
#define NCC 4

__device__ __forceinline__ float fast_tanh(float x) {
    // 1 - 2/(1+exp(2x)); saturates correctly for |x| large (exp->0 or inf)
    float e = __expf(2.0f * x);
    return 1.0f - 2.0f / (e + 1.0f);
}

__device__ __forceinline__ float waveReduce(float v) {
#pragma unroll
    for (int off = 32; off; off >>= 1) v += __shfl_down(v, off);
    return v;
}

// ---------------------------------------------------------------- mask compaction
__global__ void mask_compact(const float* __restrict__ p_mask,
                             int* __restrict__ actList, int* __restrict__ inactList,
                             int* __restrict__ counts) {
    const int b = blockIdx.x;
    const int lane = threadIdx.x;           // blockDim = 64 (one wave)
    int nA = 0, nI = 0;                     // uniform across lanes
    for (int base = 0; base < NN; base += 64) {
        int i = base + lane;
        bool act = (i < NP) ? (p_mask[b * NP + i] > 0.0f) : true;  // c_node row active
        unsigned long long mAct = __ballot(act);
        unsigned long long below = (1ull << lane) - 1ull;
        int pa = __popcll(mAct & below);
        int pi = __popcll((~mAct) & below);
        if (act) actList[b * NN + nA + pa] = i;
        else     inactList[b * NN + nI + pi] = i;
        int ca = __popcll(mAct);
        nA += ca;
        nI += 64 - ca;
    }
    if (lane == 0) { counts[b * 2] = nA; counts[b * 2 + 1] = nI; }
}

// ---------------------------------------------------------------- qk = feat @ W^T
// 128x128 tile, BK=8, 256 threads, 8x8 per thread. fp32.
__global__ __launch_bounds__(256) void gemm_qk(
    const float* __restrict__ feature, const float* __restrict__ c_node,
    const float* __restrict__ feat1, const float* __restrict__ W_gat,
    float* __restrict__ qkOut, const int layer) {
    const int nt = blockIdx.x;   // 0..5   (e tiles)
    const int mt = blockIdx.y;   // 0..15  (n tiles)
    const int gb = blockIdx.z;   // g*4+b
    const int g = gb >> 2, b = gb & 3;
    const int t = threadIdx.x;
    const int tx = t & 15, ty = t >> 4;

    __shared__ float a_s[8][128];
    __shared__ float b_s[8][128];

    const int lrow = t >> 1;
    const int kq = (t & 1) * 4;
    const int arow = mt * 128 + lrow;
    const int brow = nt * 128 + lrow;

    const float* Aptr;
    if (layer == 0)
        Aptr = (arow < NP) ? feature + ((size_t)b * NP + arow) * DD
                           : c_node + (size_t)b * DD;
    else
        Aptr = feat1 + ((size_t)gb * NN + arow) * DD;
    const float* Bptr = W_gat + (size_t)g * DD * DD + (size_t)brow * DD;

    float acc[8][8] = {};

    for (int k0 = 0; k0 < DD; k0 += 8) {
        float4 av = *(const float4*)(Aptr + k0 + kq);
        float4 bv = *(const float4*)(Bptr + k0 + kq);
        __syncthreads();   // previous iteration's reads complete
        a_s[kq + 0][lrow] = av.x; a_s[kq + 1][lrow] = av.y;
        a_s[kq + 2][lrow] = av.z; a_s[kq + 3][lrow] = av.w;
        b_s[kq + 0][lrow] = bv.x; b_s[kq + 1][lrow] = bv.y;
        b_s[kq + 2][lrow] = bv.z; b_s[kq + 3][lrow] = bv.w;
        __syncthreads();
#pragma unroll
        for (int kk = 0; kk < 8; kk++) {
            float af[8], bf[8];
            *(float4*)(af + 0) = *(const float4*)&a_s[kk][ty * 8 + 0];
            *(float4*)(af + 4) = *(const float4*)&a_s[kk][ty * 8 + 4];
            *(float4*)(bf + 0) = *(const float4*)&b_s[kk][tx * 8 + 0];
            *(float4*)(bf + 4) = *(const float4*)&b_s[kk][tx * 8 + 4];
#pragma unroll
            for (int i = 0; i < 8; i++)
#pragma unroll
                for (int j = 0; j < 8; j++)
                    acc[i][j] = fmaf(af[i], bf[j], acc[i][j]);
        }
    }

    float* outBase = qkOut + (size_t)gb * NN * DD;
#pragma unroll
    for (int i = 0; i < 8; i++) {
        float* orow = outBase + (size_t)(mt * 128 + ty * 8 + i) * DD + nt * 128 + tx * 8;
        float4 o0, o1;
        o0.x = acc[i][0]; o0.y = acc[i][1]; o0.z = acc[i][2]; o0.w = acc[i][3];
        o1.x = acc[i][4]; o1.y = acc[i][5]; o1.z = acc[i][6]; o1.w = acc[i][7];
        *(float4*)orow = o0;
        *(float4*)(orow + 4) = o1;
    }
}

// ---------------------------------------------------------------- sq, sk per row
// 256 threads = 4 waves, one wave per row.
__global__ __launch_bounds__(256) void sqsk(
    const float* __restrict__ qk, const float* __restrict__ attn_w,
    float* __restrict__ sq, float* __restrict__ sk) {
    const int gb = blockIdx.y, g = gb >> 2;
    const int w = threadIdx.x >> 6, lane = threadIdx.x & 63;
    const int n = blockIdx.x * 4 + w;
    const float* row = qk + ((size_t)gb * NN + n) * DD;
    const float* aw = attn_w + (size_t)g * HH * 2 * DHH;
#pragma unroll
    for (int h = 0; h < HH; h++) {
        float2 v = *(const float2*)(row + h * DHH + lane * 2);
        float q = v.x * aw[h * 256 + lane * 2] + v.y * aw[h * 256 + lane * 2 + 1];
        float k2 = v.x * aw[h * 256 + 128 + lane * 2] + v.y * aw[h * 256 + 128 + lane * 2 + 1];
        q = waveReduce(q);
        k2 = waveReduce(k2);
        if (lane == 0) {
            sq[((size_t)gb * NN + n) * HH + h] = q;
            sk[((size_t)gb * NN + n) * HH + h] = k2;
        }
    }
}

// ---------------------------------------------------------------- column sums of qk
__global__ __launch_bounds__(256) void colsum_part(const float* __restrict__ qk,
                                                   float* __restrict__ S_part) {
    const int gb = blockIdx.y;
    const int d = blockIdx.x * 256 + threadIdx.x;
    const int ch = blockIdx.z;
    const float* p = qk + ((size_t)gb * NN + (size_t)ch * 256) * DD + d;
    float s0 = 0, s1 = 0, s2 = 0, s3 = 0;
    for (int n = 0; n < 256; n += 4) {
        s0 += p[0];
        s1 += p[(size_t)DD];
        s2 += p[(size_t)2 * DD];
        s3 += p[(size_t)3 * DD];
        p += (size_t)4 * DD;
    }
    S_part[((size_t)gb * 8 + ch) * DD + d] = ((s0 + s1) + (s2 + s3));
}

__global__ __launch_bounds__(256) void finishS(const float* __restrict__ S_part,
                                               float* __restrict__ S_all,
                                               float* __restrict__ hidU) {
    const int gb = blockIdx.y;
    const int d = blockIdx.x * 256 + threadIdx.x;
    float s = 0;
#pragma unroll
    for (int c = 0; c < 8; c++) s += S_part[((size_t)gb * 8 + c) * DD + d];
    S_all[(size_t)gb * DD + d] = s;
    hidU[(size_t)gb * DD + d] = fast_tanh(s * (1.0f / 2048.0f));
}

// ---------------------------------------------------------------- masked-q rows (layer 1)
__global__ __launch_bounds__(256) void update_inactive(
    const float* __restrict__ feature, const float* __restrict__ c_node,
    const float* __restrict__ hidU, const int* __restrict__ inactList,
    const int* __restrict__ counts, float* __restrict__ feat1) {
    const int gb = blockIdx.y, b = gb & 3;
    const int idx = blockIdx.x;
    if (idx >= counts[b * 2 + 1]) return;
    const int n = inactList[b * NN + idx];
    const float* src = (n < NP) ? feature + ((size_t)b * NP + n) * DD
                                : c_node + (size_t)b * DD;
    const float* hu = hidU + (size_t)gb * DD;
    float* dst = feat1 + ((size_t)gb * NN + n) * DD;
    for (int d = threadIdx.x; d < DD; d += 256) dst[d] = src[d] + hu[d];
}

// ---------------------------------------------------------------- active-q attention (layer 1)
// Per block: 64 active q rows x 128 cols (one head), loop over active k tiles of 64.
__global__ __launch_bounds__(256) void attn_active(
    const float* __restrict__ qk, const float* __restrict__ sq,
    const float* __restrict__ sk, const float* __restrict__ S_all,
    const float* __restrict__ feature, const float* __restrict__ c_node,
    const int* __restrict__ actList, const int* __restrict__ counts,
    float* __restrict__ feat1) {
    const int gb = blockIdx.z, b = gb & 3;
    const int h = blockIdx.y;
    const int qt = blockIdx.x;
    const int nAct = counts[b * 2];
    if (qt * 64 >= nAct) return;

    __shared__ float e_s[64][68];     // [kk][q], padded for bank spread + alignment
    __shared__ float v_s[64][132];    // [kk][c]
    __shared__ float sq_s[64];
    __shared__ float sk_s[64];
    __shared__ int qIdx[64];
    __shared__ float dsum_s[4][64];

    const int t = threadIdx.x;
    const int tx = t & 15, ty = t >> 4;

    if (t < 64) {
        int jj = qt * 64 + t;
        int qn = actList[b * NN + (jj < nAct ? jj : nAct - 1)];
        qIdx[t] = (jj < nAct) ? qn : -1;
        sq_s[t] = sq[((size_t)gb * NN + qn) * HH + h];
    }
    __syncthreads();

    float acc[4][8] = {};
    float dsum = 0.0f;
    const int eq = t & 63, eseg = t >> 6;
    const float my_sq = sq_s[eq];
    const int vr = t >> 2, vp = t & 3;

    for (int kt = 0; kt * 64 < nAct; kt++) {
        // stage v tile (global -> regs, issued before barrier)
        int jj = kt * 64 + vr;
        int kn = actList[b * NN + (jj < nAct ? jj : nAct - 1)];
        const float* vrow = qk + ((size_t)gb * NN + kn) * DD + h * DHH + vp * 32;
        float4 vv[8];
#pragma unroll
        for (int j = 0; j < 8; j++) vv[j] = *(const float4*)(vrow + j * 4);

        float skv = 0.0f;
        if (t < 64) {
            int jk = kt * 64 + t;
            int kn2 = actList[b * NN + (jk < nAct ? jk : nAct - 1)];
            skv = sk[((size_t)gb * NN + kn2) * HH + h];
        }
        __syncthreads();   // prior tile's LDS reads complete
#pragma unroll
        for (int j = 0; j < 8; j++) *(float4*)&v_s[vr][vp * 32 + j * 4] = vv[j];
        if (t < 64) sk_s[t] = skv;
        __syncthreads();

        // e tile: 16 values per thread (fixed q = eq)
#pragma unroll 4
        for (int kk = eseg * 16; kk < eseg * 16 + 16; kk++) {
            float e = 0.0f;
            if (kt * 64 + kk < nAct) e = __expf(fast_tanh(my_sq + sk_s[kk])) - 1.0f;
            e_s[kk][eq] = e;
            dsum += e;
        }
        __syncthreads();

        // FMA: acc[i][j] += e[q][kk] * v[kk][c]
#pragma unroll 8
        for (int kk = 0; kk < 64; kk++) {
            float ef[4], vf[8];
            *(float4*)ef = *(const float4*)&e_s[kk][ty * 4];
            *(float4*)(vf + 0) = *(const float4*)&v_s[kk][tx * 8 + 0];
            *(float4*)(vf + 4) = *(const float4*)&v_s[kk][tx * 8 + 4];
#pragma unroll
            for (int i = 0; i < 4; i++)
#pragma unroll
                for (int j = 0; j < 8; j++)
                    acc[i][j] = fmaf(ef[i], vf[j], acc[i][j]);
        }
    }

    dsum_s[eseg][eq] = dsum;
    __syncthreads();

    const float* Sp = S_all + (size_t)gb * DD + h * DHH;
#pragma unroll
    for (int i = 0; i < 4; i++) {
        int q = ty * 4 + i;
        int qn = qIdx[q];
        if (qn < 0) continue;
        float denom = 2048.0f + dsum_s[0][q] + dsum_s[1][q] + dsum_s[2][q] + dsum_s[3][q];
        float rden = 1.0f / denom;
        const float* res = (qn < NP) ? feature + ((size_t)b * NP + qn) * DD
                                     : c_node + (size_t)b * DD;
        float* dst = feat1 + ((size_t)gb * NN + qn) * DD + h * DHH;
#pragma unroll
        for (int j = 0; j < 8; j++) {
            int c = tx * 8 + j;
            float hid = fast_tanh((acc[i][j] + Sp[c]) * rden);
            dst[c] = res[h * DHH + c] + hid;
        }
    }
}

// ---------------------------------------------------------------- layer-2 attention, q = N-1 only
__global__ __launch_bounds__(128) void attn_final(
    const float* __restrict__ qk, const float* __restrict__ sq,
    const float* __restrict__ sk, const float* __restrict__ S_all,
    const float* __restrict__ feat1, const int* __restrict__ actList,
    const int* __restrict__ counts, float* __restrict__ gout) {
    const int h = blockIdx.x;
    const int gb = blockIdx.y, b = gb & 3;
    const int t = threadIdx.x;     // 128 threads = d within head
    const int nAct = counts[b * 2];
    const float my_sq = sq[((size_t)gb * NN + (NN - 1)) * HH + h];
    float acc = 0.0f, wsum = 0.0f;
    for (int j = 0; j < nAct; j++) {
        int k = actList[b * NN + j];
        float e = __expf(fast_tanh(my_sq + sk[((size_t)gb * NN + k) * HH + h])) - 1.0f;
        acc = fmaf(e, qk[((size_t)gb * NN + k) * DD + h * DHH + t], acc);
        wsum += e;
    }
    float numer = acc + S_all[(size_t)gb * DD + h * DHH + t];
    float denom = 2048.0f + wsum;
    float hid = fast_tanh(numer / denom);
    gout[(size_t)gb * DD + h * DHH + t] =
        feat1[((size_t)gb * NN + (NN - 1)) * DD + h * DHH + t] + hid;
}

// ---------------------------------------------------------------- MLP head + logits
__global__ __launch_bounds__(256) void mlp_head(
    const float* __restrict__ gout, const float* __restrict__ w0,
    const float* __restrict__ b0, const float* __restrict__ w1,
    const float* __restrict__ b1, const float* __restrict__ fcw,
    const float* __restrict__ fcb, float* __restrict__ out) {
    const int gb = blockIdx.x, g = gb >> 2, b = gb & 3;
    __shared__ float xbuf[FHH];
    __shared__ float ybuf[FHH];
    const int t = threadIdx.x, w = t >> 6, lane = t & 63;

    for (int d = t; d < DD; d += 256) xbuf[d] = gout[(size_t)gb * DD + d];
    __syncthreads();

    for (int f = w; f < FHH; f += 4) {
        const float* row = w0 + (size_t)f * DD;
        float s = 0;
        for (int d = lane; d < DD; d += 64) s = fmaf(row[d], xbuf[d], s);
        s = waveReduce(s);
        if (lane == 0) ybuf[f] = fmaxf(s + b0[f], 0.0f);
    }
    __syncthreads();

    for (int f = w; f < FHH; f += 4) {
        const float* row = w1 + (size_t)f * FHH;
        float s = 0;
        for (int d = lane; d < FHH; d += 64) s = fmaf(row[d], ybuf[d], s);
        s = waveReduce(s);
        if (lane == 0) xbuf[f] = fmaxf(s + b1[f], 0.0f);
    }
    __syncthreads();

    if (w < NCC) {
        const float* row = fcw + ((size_t)g * NCC + w) * FHH;
        float s = 0;
        for (int d = lane; d < FHH; d += 64) s = fmaf(row[d], xbuf[d], s);
        s = waveReduce(s);
        if (lane == 0) out[g * (BB * NCC) + b * NCC + w] = s + fcb[g * NCC + w];
    }
}

extern "C" void kernel_launch(void* const* d_in, const int* in_sizes, int n_in,
                              void* d_out, int out_size, void* d_ws, size_t ws_size,
                              hipStream_t stream) {
    const float* p_mask  = (const float*)d_in[0];
    const float* feature = (const float*)d_in[1];
    const float* c_node  = (const float*)d_in[2];
    const float* W_gat   = (const float*)d_in[3];
    const float* attn_w  = (const float*)d_in[4];
    const float* w0      = (const float*)d_in[5];
    const float* b0      = (const float*)d_in[6];
    const float* w1      = (const float*)d_in[7];
    const float* b1      = (const float*)d_in[8];
    const float* fcw     = (const float*)d_in[9];
    const float* fcb     = (const float*)d_in[10];
    float* out = (float*)d_out;

    // workspace carve-up (~204 MB)
    float* fw = (float*)d_ws;
    size_t off = 0;
    float* feat1  = fw + off; off += (size_t)16 * NN * DD;
    float* qk     = fw + off; off += (size_t)16 * NN * DD;
    float* sq     = fw + off; off += (size_t)16 * NN * HH;
    float* sk     = fw + off; off += (size_t)16 * NN * HH;
    float* S_part = fw + off; off += (size_t)16 * 8 * DD;
    float* S_all  = fw + off; off += (size_t)16 * DD;
    float* hidU   = fw + off; off += (size_t)16 * DD;
    float* gout   = fw + off; off += (size_t)16 * DD;
    int* actList   = (int*)(fw + off); off += (size_t)BB * NN;
    int* inactList = (int*)(fw + off); off += (size_t)BB * NN;
    int* counts    = (int*)(fw + off); off += 16;

    mask_compact<<<dim3(BB), dim3(64), 0, stream>>>(p_mask, actList, inactList, counts);

    // -------- layer 1
    gemm_qk<<<dim3(6, 16, 16), dim3(256), 0, stream>>>(feature, c_node, feat1, W_gat, qk, 0);
    sqsk<<<dim3(NN / 4, 16), dim3(256), 0, stream>>>(qk, attn_w, sq, sk);
    colsum_part<<<dim3(3, 16, 8), dim3(256), 0, stream>>>(qk, S_part);
    finishS<<<dim3(3, 16), dim3(256), 0, stream>>>(S_part, S_all, hidU);
    update_inactive<<<dim3(NN, 16), dim3(256), 0, stream>>>(feature, c_node, hidU,
                                                            inactList, counts, feat1);
    attn_active<<<dim3(32, HH, 16), dim3(256), 0, stream>>>(qk, sq, sk, S_all, feature,
                                                            c_node, actList, counts, feat1);

    // -------- layer 2 (attention only needed for q = N-1)
    gemm_qk<<<dim3(6, 16, 16), dim3(256), 0, stream>>>(feature, c_node, feat1, W_gat, qk, 1);
    sqsk<<<dim3(NN / 4, 16), dim3(256), 0, stream>>>(qk, attn_w, sq, sk);
    colsum_part<<<dim3(3, 16, 8), dim3(256), 0, stream>>>(qk, S_part);
    finishS<<<dim3(3, 16), dim3(256), 0, stream>>>(S_part, S_all, hidU);
    attn_final<<<dim3(HH, 16), dim3(128), 0, stream>>>(qk, sq, sk, S_all, feat1,
                                                       actList, counts, gout);

    mlp_head<<<dim3(16), dim3(256), 0, stream>>>(gout, w0, b0, w1, b1, fcw, fcb, out);
}

// Round 4
// 1722.632 us; speedup vs baseline: 2.4807x; 2.4807x over previous
//
#include <hip/hip_runtime.h>
#include <hip/hip_bf16.h>

// MultiGAT on MI355X — round 3: resubmit of round-2 (two GPUAcquisitionTimeouts;
// rounds 1-2 changes still unmeasured — do not stack a third unverified change).
//  r1: MLP head -> 3 grid-parallel GEMV kernels (was 1780 us at 0.17% VALUBusy).
//  r2: projection GEMM qk = feat @ W^T on MFMA via split-bf16 3-pass
//      (hi*hi + hi*lo + lo*hi), err ~1e-5. W pre-split once; A split on the fly.
//      128x128 tile, BK=32, LDS stride 40 ush (16B-aligned, bank-spread).
//
// Math restructuring vs reference (exact up to fp reassociation):
//  - MASK_FILL = -1e-8  =>  exp(-1e-8) == 1.0f exactly in fp32. So softmax:
//       active q:  numer[d] = S_all[d] + sum_{active k} (exp(tanh(sq+sk))-1)*qk[k,d]
//                  denom    = 2048 + sum_{active k} (exp(tanh(..))-1)
//       masked q:  uniform attn -> hid = tanh(S_all/2048)
//  - Output uses only row N-1 after layer 2, so layer-2 attention is 1 q-row.

#define BB 4
#define NP 2047
#define NN 2048
#define DD 768
#define HH 6
#define DHH 128
#define FHH 768
#define NCC 4

typedef __attribute__((ext_vector_type(8))) short bf16x8;
typedef __attribute__((ext_vector_type(4))) float f32x4;

__device__ __forceinline__ float fast_tanh(float x) {
    float e = __expf(2.0f * x);
    return 1.0f - 2.0f / (e + 1.0f);
}

__device__ __forceinline__ float waveReduce(float v) {
#pragma unroll
    for (int off = 32; off; off >>= 1) v += __shfl_down(v, off);
    return v;
}

__device__ __forceinline__ unsigned short f2bf(float x) {   // RNE
    unsigned int u = __float_as_uint(x);
    unsigned int r = u + 0x7FFFu + ((u >> 16) & 1u);
    return (unsigned short)(r >> 16);
}
__device__ __forceinline__ float bf2f(unsigned short h) {
    return __uint_as_float((unsigned int)h << 16);
}

// ---------------------------------------------------------------- mask compaction
__global__ void mask_compact(const float* __restrict__ p_mask,
                             int* __restrict__ actList, int* __restrict__ inactList,
                             int* __restrict__ counts) {
    const int b = blockIdx.x;
    const int lane = threadIdx.x;           // blockDim = 64 (one wave)
    int nA = 0, nI = 0;
    for (int base = 0; base < NN; base += 64) {
        int i = base + lane;
        bool act = (i < NP) ? (p_mask[b * NP + i] > 0.0f) : true;
        unsigned long long mAct = __ballot(act);
        unsigned long long below = (1ull << lane) - 1ull;
        int pa = __popcll(mAct & below);
        int pi = __popcll((~mAct) & below);
        if (act) actList[b * NN + nA + pa] = i;
        else     inactList[b * NN + nI + pi] = i;
        int ca = __popcll(mAct);
        nA += ca;
        nI += 64 - ca;
    }
    if (lane == 0) { counts[b * 2] = nA; counts[b * 2 + 1] = nI; }
}

// ---------------------------------------------------------------- W split: fp32 -> bf16 hi/lo
__global__ __launch_bounds__(256) void split_w(const float* __restrict__ W,
                                               unsigned short* __restrict__ hi,
                                               unsigned short* __restrict__ lo) {
    size_t i = ((size_t)blockIdx.x * 256 + threadIdx.x) * 4;
    float4 v = *(const float4*)(W + i);
    unsigned short h0 = f2bf(v.x), h1 = f2bf(v.y), h2 = f2bf(v.z), h3 = f2bf(v.w);
    unsigned short l0 = f2bf(v.x - bf2f(h0)), l1 = f2bf(v.y - bf2f(h1));
    unsigned short l2 = f2bf(v.z - bf2f(h2)), l3 = f2bf(v.w - bf2f(h3));
    uint2 hw, lw;
    hw.x = (unsigned)h0 | ((unsigned)h1 << 16); hw.y = (unsigned)h2 | ((unsigned)h3 << 16);
    lw.x = (unsigned)l0 | ((unsigned)l1 << 16); lw.y = (unsigned)l2 | ((unsigned)l3 << 16);
    *(uint2*)(hi + i) = hw;
    *(uint2*)(lo + i) = lw;
}

// ---------------------------------------------------------------- qk = feat @ W^T (MFMA, split-bf16)
// grid (6, 16, 16), 256 thr = 4 waves (2x2), tile 128x128, BK=32.
// LDS stride padded to 40 ush (80 B) -> 16B-aligned, bank-spread.
#define LDK 40
__global__ __launch_bounds__(256, 2) void gemm_qk_mfma(
    const float* __restrict__ feature, const float* __restrict__ c_node,
    const float* __restrict__ feat1, const unsigned short* __restrict__ Whi,
    const unsigned short* __restrict__ Wlo, float* __restrict__ qkOut,
    const int layer) {
    const int nt = blockIdx.x;   // 0..5   e-tile
    const int mt = blockIdx.y;   // 0..15  n-tile
    const int gb = blockIdx.z;   // g*4+b
    const int g = gb >> 2, b = gb & 3;
    const int t = threadIdx.x;

    __shared__ unsigned short Ahi[128][LDK], Alo[128][LDK];
    __shared__ unsigned short Bhi[128][LDK], Blo[128][LDK];

    // staging assignment: 2 threads per row, 16 K-elems each
    const int srow = t >> 1;
    const int skq = (t & 1) * 16;
    const float* Arow;
    if (layer == 0) {
        int grow = mt * 128 + srow;
        Arow = (grow < NP) ? feature + ((size_t)b * NP + grow) * DD
                           : c_node + (size_t)b * DD;
    } else {
        Arow = feat1 + ((size_t)gb * NN + mt * 128 + srow) * DD;
    }
    const unsigned short* BrowH = Whi + ((size_t)g * DD + nt * 128 + srow) * DD;
    const unsigned short* BrowL = Wlo + ((size_t)g * DD + nt * 128 + srow) * DD;

    const int wv = t >> 6, lane = t & 63;
    const int wr = wv >> 1, wc = wv & 1;
    const int fr = lane & 15, kg = lane >> 4;

    f32x4 acc[4][4] = {};

    for (int k0 = 0; k0 < DD; k0 += 32) {
        // global loads (issue early)
        float af[16];
        *(float4*)(af + 0)  = *(const float4*)(Arow + k0 + skq + 0);
        *(float4*)(af + 4)  = *(const float4*)(Arow + k0 + skq + 4);
        *(float4*)(af + 8)  = *(const float4*)(Arow + k0 + skq + 8);
        *(float4*)(af + 12) = *(const float4*)(Arow + k0 + skq + 12);
        uint4 bh0 = *(const uint4*)(BrowH + k0 + skq);
        uint4 bh1 = *(const uint4*)(BrowH + k0 + skq + 8);
        uint4 bl0 = *(const uint4*)(BrowL + k0 + skq);
        uint4 bl1 = *(const uint4*)(BrowL + k0 + skq + 8);

        __syncthreads();   // prior iteration's LDS reads complete

        unsigned int hiw[8], low[8];
#pragma unroll
        for (int p = 0; p < 8; p++) {
            float x0 = af[2 * p], x1 = af[2 * p + 1];
            unsigned short h0 = f2bf(x0), h1 = f2bf(x1);
            unsigned short l0 = f2bf(x0 - bf2f(h0)), l1 = f2bf(x1 - bf2f(h1));
            hiw[p] = (unsigned)h0 | ((unsigned)h1 << 16);
            low[p] = (unsigned)l0 | ((unsigned)l1 << 16);
        }
        *(uint4*)&Ahi[srow][skq + 0] = make_uint4(hiw[0], hiw[1], hiw[2], hiw[3]);
        *(uint4*)&Ahi[srow][skq + 8] = make_uint4(hiw[4], hiw[5], hiw[6], hiw[7]);
        *(uint4*)&Alo[srow][skq + 0] = make_uint4(low[0], low[1], low[2], low[3]);
        *(uint4*)&Alo[srow][skq + 8] = make_uint4(low[4], low[5], low[6], low[7]);
        *(uint4*)&Bhi[srow][skq + 0] = bh0;
        *(uint4*)&Bhi[srow][skq + 8] = bh1;
        *(uint4*)&Blo[srow][skq + 0] = bl0;
        *(uint4*)&Blo[srow][skq + 8] = bl1;

        __syncthreads();

        bf16x8 bh[4], bl[4];
#pragma unroll
        for (int j = 0; j < 4; j++) {
            int row = wc * 64 + j * 16 + fr;
            bh[j] = *(const bf16x8*)&Bhi[row][kg * 8];
            bl[j] = *(const bf16x8*)&Blo[row][kg * 8];
        }
#pragma unroll
        for (int i = 0; i < 4; i++) {
            int row = wr * 64 + i * 16 + fr;
            bf16x8 ah = *(const bf16x8*)&Ahi[row][kg * 8];
            bf16x8 al = *(const bf16x8*)&Alo[row][kg * 8];
#pragma unroll
            for (int j = 0; j < 4; j++) {
                acc[i][j] = __builtin_amdgcn_mfma_f32_16x16x32_bf16(ah, bh[j], acc[i][j], 0, 0, 0);
                acc[i][j] = __builtin_amdgcn_mfma_f32_16x16x32_bf16(ah, bl[j], acc[i][j], 0, 0, 0);
                acc[i][j] = __builtin_amdgcn_mfma_f32_16x16x32_bf16(al, bh[j], acc[i][j], 0, 0, 0);
            }
        }
    }

    // epilogue: C/D layout col=lane&15, row=(lane>>4)*4+reg  [m89-verified]
    float* outB = qkOut + (size_t)gb * NN * DD;
#pragma unroll
    for (int i = 0; i < 4; i++) {
#pragma unroll
        for (int j = 0; j < 4; j++) {
            int rbase = mt * 128 + wr * 64 + i * 16 + kg * 4;
            int cbase = nt * 128 + wc * 64 + j * 16 + fr;
#pragma unroll
            for (int r = 0; r < 4; r++)
                outB[(size_t)(rbase + r) * DD + cbase] = acc[i][j][r];
        }
    }
}

// ---------------------------------------------------------------- sq, sk per row
__global__ __launch_bounds__(256) void sqsk(
    const float* __restrict__ qk, const float* __restrict__ attn_w,
    float* __restrict__ sq, float* __restrict__ sk) {
    const int gb = blockIdx.y, g = gb >> 2;
    const int w = threadIdx.x >> 6, lane = threadIdx.x & 63;
    const int n = blockIdx.x * 4 + w;
    const float* row = qk + ((size_t)gb * NN + n) * DD;
    const float* aw = attn_w + (size_t)g * HH * 2 * DHH;
#pragma unroll
    for (int h = 0; h < HH; h++) {
        float2 v = *(const float2*)(row + h * DHH + lane * 2);
        float q = v.x * aw[h * 256 + lane * 2] + v.y * aw[h * 256 + lane * 2 + 1];
        float k2 = v.x * aw[h * 256 + 128 + lane * 2] + v.y * aw[h * 256 + 128 + lane * 2 + 1];
        q = waveReduce(q);
        k2 = waveReduce(k2);
        if (lane == 0) {
            sq[((size_t)gb * NN + n) * HH + h] = q;
            sk[((size_t)gb * NN + n) * HH + h] = k2;
        }
    }
}

// ---------------------------------------------------------------- column sums of qk
__global__ __launch_bounds__(256) void colsum_part(const float* __restrict__ qk,
                                                   float* __restrict__ S_part) {
    const int gb = blockIdx.y;
    const int d = blockIdx.x * 256 + threadIdx.x;
    const int ch = blockIdx.z;
    const float* p = qk + ((size_t)gb * NN + (size_t)ch * 256) * DD + d;
    float s0 = 0, s1 = 0, s2 = 0, s3 = 0;
    for (int n = 0; n < 256; n += 4) {
        s0 += p[0];
        s1 += p[(size_t)DD];
        s2 += p[(size_t)2 * DD];
        s3 += p[(size_t)3 * DD];
        p += (size_t)4 * DD;
    }
    S_part[((size_t)gb * 8 + ch) * DD + d] = ((s0 + s1) + (s2 + s3));
}

__global__ __launch_bounds__(256) void finishS(const float* __restrict__ S_part,
                                               float* __restrict__ S_all,
                                               float* __restrict__ hidU) {
    const int gb = blockIdx.y;
    const int d = blockIdx.x * 256 + threadIdx.x;
    float s = 0;
#pragma unroll
    for (int c = 0; c < 8; c++) s += S_part[((size_t)gb * 8 + c) * DD + d];
    S_all[(size_t)gb * DD + d] = s;
    hidU[(size_t)gb * DD + d] = fast_tanh(s * (1.0f / 2048.0f));
}

// ---------------------------------------------------------------- masked-q rows (layer 1)
__global__ __launch_bounds__(256) void update_inactive(
    const float* __restrict__ feature, const float* __restrict__ c_node,
    const float* __restrict__ hidU, const int* __restrict__ inactList,
    const int* __restrict__ counts, float* __restrict__ feat1) {
    const int gb = blockIdx.y, b = gb & 3;
    const int idx = blockIdx.x;
    if (idx >= counts[b * 2 + 1]) return;
    const int n = inactList[b * NN + idx];
    const float* src = (n < NP) ? feature + ((size_t)b * NP + n) * DD
                                : c_node + (size_t)b * DD;
    const float* hu = hidU + (size_t)gb * DD;
    float* dst = feat1 + ((size_t)gb * NN + n) * DD;
    for (int d = threadIdx.x; d < DD; d += 256) dst[d] = src[d] + hu[d];
}

// ---------------------------------------------------------------- active-q attention (layer 1)
__global__ __launch_bounds__(256) void attn_active(
    const float* __restrict__ qk, const float* __restrict__ sq,
    const float* __restrict__ sk, const float* __restrict__ S_all,
    const float* __restrict__ feature, const float* __restrict__ c_node,
    const int* __restrict__ actList, const int* __restrict__ counts,
    float* __restrict__ feat1) {
    const int gb = blockIdx.z, b = gb & 3;
    const int h = blockIdx.y;
    const int qt = blockIdx.x;
    const int nAct = counts[b * 2];
    if (qt * 64 >= nAct) return;

    __shared__ float e_s[64][68];     // [kk][q]
    __shared__ float v_s[64][132];    // [kk][c]
    __shared__ float sq_s[64];
    __shared__ float sk_s[64];
    __shared__ int qIdx[64];
    __shared__ float dsum_s[4][64];

    const int t = threadIdx.x;
    const int tx = t & 15, ty = t >> 4;

    if (t < 64) {
        int jj = qt * 64 + t;
        int qn = actList[b * NN + (jj < nAct ? jj : nAct - 1)];
        qIdx[t] = (jj < nAct) ? qn : -1;
        sq_s[t] = sq[((size_t)gb * NN + qn) * HH + h];
    }
    __syncthreads();

    float acc[4][8] = {};
    float dsum = 0.0f;
    const int eq = t & 63, eseg = t >> 6;
    const float my_sq = sq_s[eq];
    const int vr = t >> 2, vp = t & 3;

    for (int kt = 0; kt * 64 < nAct; kt++) {
        int jj = kt * 64 + vr;
        int kn = actList[b * NN + (jj < nAct ? jj : nAct - 1)];
        const float* vrow = qk + ((size_t)gb * NN + kn) * DD + h * DHH + vp * 32;
        float4 vv[8];
#pragma unroll
        for (int j = 0; j < 8; j++) vv[j] = *(const float4*)(vrow + j * 4);

        float skv = 0.0f;
        if (t < 64) {
            int jk = kt * 64 + t;
            int kn2 = actList[b * NN + (jk < nAct ? jk : nAct - 1)];
            skv = sk[((size_t)gb * NN + kn2) * HH + h];
        }
        __syncthreads();
#pragma unroll
        for (int j = 0; j < 8; j++) *(float4*)&v_s[vr][vp * 32 + j * 4] = vv[j];
        if (t < 64) sk_s[t] = skv;
        __syncthreads();

#pragma unroll 4
        for (int kk = eseg * 16; kk < eseg * 16 + 16; kk++) {
            float e = 0.0f;
            if (kt * 64 + kk < nAct) e = __expf(fast_tanh(my_sq + sk_s[kk])) - 1.0f;
            e_s[kk][eq] = e;
            dsum += e;
        }
        __syncthreads();

#pragma unroll 8
        for (int kk = 0; kk < 64; kk++) {
            float ef[4], vf[8];
            *(float4*)ef = *(const float4*)&e_s[kk][ty * 4];
            *(float4*)(vf + 0) = *(const float4*)&v_s[kk][tx * 8 + 0];
            *(float4*)(vf + 4) = *(const float4*)&v_s[kk][tx * 8 + 4];
#pragma unroll
            for (int i = 0; i < 4; i++)
#pragma unroll
                for (int j = 0; j < 8; j++)
                    acc[i][j] = fmaf(ef[i], vf[j], acc[i][j]);
        }
    }

    dsum_s[eseg][eq] = dsum;
    __syncthreads();

    const float* Sp = S_all + (size_t)gb * DD + h * DHH;
#pragma unroll
    for (int i = 0; i < 4; i++) {
        int q = ty * 4 + i;
        int qn = qIdx[q];
        if (qn < 0) continue;
        float denom = 2048.0f + dsum_s[0][q] + dsum_s[1][q] + dsum_s[2][q] + dsum_s[3][q];
        float rden = 1.0f / denom;
        const float* res = (qn < NP) ? feature + ((size_t)b * NP + qn) * DD
                                     : c_node + (size_t)b * DD;
        float* dst = feat1 + ((size_t)gb * NN + qn) * DD + h * DHH;
#pragma unroll
        for (int j = 0; j < 8; j++) {
            int c = tx * 8 + j;
            float hid = fast_tanh((acc[i][j] + Sp[c]) * rden);
            dst[c] = res[h * DHH + c] + hid;
        }
    }
}

// ---------------------------------------------------------------- layer-2 attention, q = N-1 only
__global__ __launch_bounds__(128) void attn_final(
    const float* __restrict__ qk, const float* __restrict__ sq,
    const float* __restrict__ sk, const float* __restrict__ S_all,
    const float* __restrict__ feat1, const int* __restrict__ actList,
    const int* __restrict__ counts, float* __restrict__ gout) {
    const int h = blockIdx.x;
    const int gb = blockIdx.y, b = gb & 3;
    const int t = threadIdx.x;
    const int nAct = counts[b * 2];
    const float my_sq = sq[((size_t)gb * NN + (NN - 1)) * HH + h];
    float acc = 0.0f, wsum = 0.0f;
    for (int j = 0; j < nAct; j++) {
        int k = actList[b * NN + j];
        float e = __expf(fast_tanh(my_sq + sk[((size_t)gb * NN + k) * HH + h])) - 1.0f;
        acc = fmaf(e, qk[((size_t)gb * NN + k) * DD + h * DHH + t], acc);
        wsum += e;
    }
    float numer = acc + S_all[(size_t)gb * DD + h * DHH + t];
    float denom = 2048.0f + wsum;
    float hid = fast_tanh(numer / denom);
    gout[(size_t)gb * DD + h * DHH + t] =
        feat1[((size_t)gb * NN + (NN - 1)) * DD + h * DHH + t] + hid;
}

// ---------------------------------------------------------------- MLP: grid-parallel GEMV
__global__ __launch_bounds__(256) void mlp_gemv(
    const float* __restrict__ xin, const float* __restrict__ w,
    const float* __restrict__ bias, float* __restrict__ yout) {
    const int gb = blockIdx.y;
    const int wv = threadIdx.x >> 6, lane = threadIdx.x & 63;
    const int f = blockIdx.x * 4 + wv;
    const float* row = w + (size_t)f * FHH;
    const float* x = xin + (size_t)gb * FHH;
    float s = 0.0f;
#pragma unroll
    for (int d = lane * 4; d < FHH; d += 256) {
        float4 rv = *(const float4*)(row + d);
        float4 xv = *(const float4*)(x + d);
        s += rv.x * xv.x + rv.y * xv.y + rv.z * xv.z + rv.w * xv.w;
    }
    s = waveReduce(s);
    if (lane == 0) yout[(size_t)gb * FHH + f] = fmaxf(s + bias[f], 0.0f);
}

__global__ __launch_bounds__(256) void fc_out(
    const float* __restrict__ x2, const float* __restrict__ fcw,
    const float* __restrict__ fcb, float* __restrict__ out) {
    const int gb = blockIdx.x, g = gb >> 2, b = gb & 3;
    const int wv = threadIdx.x >> 6, lane = threadIdx.x & 63;
    const float* row = fcw + ((size_t)g * NCC + wv) * FHH;
    const float* x = x2 + (size_t)gb * FHH;
    float s = 0.0f;
#pragma unroll
    for (int d = lane * 4; d < FHH; d += 256) {
        float4 rv = *(const float4*)(row + d);
        float4 xv = *(const float4*)(x + d);
        s += rv.x * xv.x + rv.y * xv.y + rv.z * xv.z + rv.w * xv.w;
    }
    s = waveReduce(s);
    if (lane == 0) out[g * (BB * NCC) + b * NCC + wv] = s + fcb[g * NCC + wv];
}

extern "C" void kernel_launch(void* const* d_in, const int* in_sizes, int n_in,
                              void* d_out, int out_size, void* d_ws, size_t ws_size,
                              hipStream_t stream) {
    const float* p_mask  = (const float*)d_in[0];
    const float* feature = (const float*)d_in[1];
    const float* c_node  = (const float*)d_in[2];
    const float* W_gat   = (const float*)d_in[3];
    const float* attn_w  = (const float*)d_in[4];
    const float* w0      = (const float*)d_in[5];
    const float* b0      = (const float*)d_in[6];
    const float* w1      = (const float*)d_in[7];
    const float* b1      = (const float*)d_in[8];
    const float* fcw     = (const float*)d_in[9];
    const float* fcb     = (const float*)d_in[10];
    float* out = (float*)d_out;

    // workspace carve-up (~214 MB)
    float* fw = (float*)d_ws;
    size_t off = 0;
    float* feat1  = fw + off; off += (size_t)16 * NN * DD;
    float* qk     = fw + off; off += (size_t)16 * NN * DD;
    float* sq     = fw + off; off += (size_t)16 * NN * HH;
    float* sk     = fw + off; off += (size_t)16 * NN * HH;
    float* S_part = fw + off; off += (size_t)16 * 8 * DD;
    float* S_all  = fw + off; off += (size_t)16 * DD;
    float* hidU   = fw + off; off += (size_t)16 * DD;
    float* gout   = fw + off; off += (size_t)16 * DD;
    float* x1     = fw + off; off += (size_t)16 * FHH;
    float* x2     = fw + off; off += (size_t)16 * FHH;
    int* actList   = (int*)(fw + off); off += (size_t)BB * NN;
    int* inactList = (int*)(fw + off); off += (size_t)BB * NN;
    int* counts    = (int*)(fw + off); off += 16;
    unsigned short* Whi = (unsigned short*)(fw + off); off += (size_t)4 * DD * DD / 2;
    unsigned short* Wlo = (unsigned short*)(fw + off); off += (size_t)4 * DD * DD / 2;

    mask_compact<<<dim3(BB), dim3(64), 0, stream>>>(p_mask, actList, inactList, counts);
    split_w<<<dim3(4 * DD * DD / 1024), dim3(256), 0, stream>>>(W_gat, Whi, Wlo);

    // -------- layer 1
    gemm_qk_mfma<<<dim3(6, 16, 16), dim3(256), 0, stream>>>(feature, c_node, feat1,
                                                            Whi, Wlo, qk, 0);
    sqsk<<<dim3(NN / 4, 16), dim3(256), 0, stream>>>(qk, attn_w, sq, sk);
    colsum_part<<<dim3(3, 16, 8), dim3(256), 0, stream>>>(qk, S_part);
    finishS<<<dim3(3, 16), dim3(256), 0, stream>>>(S_part, S_all, hidU);
    update_inactive<<<dim3(NN, 16), dim3(256), 0, stream>>>(feature, c_node, hidU,
                                                            inactList, counts, feat1);
    attn_active<<<dim3(32, HH, 16), dim3(256), 0, stream>>>(qk, sq, sk, S_all, feature,
                                                            c_node, actList, counts, feat1);

    // -------- layer 2 (attention only needed for q = N-1)
    gemm_qk_mfma<<<dim3(6, 16, 16), dim3(256), 0, stream>>>(feature, c_node, feat1,
                                                            Whi, Wlo, qk, 1);
    sqsk<<<dim3(NN / 4, 16), dim3(256), 0, stream>>>(qk, attn_w, sq, sk);
    colsum_part<<<dim3(3, 16, 8), dim3(256), 0, stream>>>(qk, S_part);
    finishS<<<dim3(3, 16), dim3(256), 0, stream>>>(S_part, S_all, hidU);
    attn_final<<<dim3(HH, 16), dim3(128), 0, stream>>>(qk, sq, sk, S_all, feat1,
                                                       actList, counts, gout);

    // -------- MLP head (grid-parallel)
    mlp_gemv<<<dim3(FHH / 4, 16), dim3(256), 0, stream>>>(gout, w0, b0, x1);
    mlp_gemv<<<dim3(FHH / 4, 16), dim3(256), 0, stream>>>(x1, w1, b1, x2);
    fc_out<<<dim3(16), dim3(256), 0, stream>>>(x2, fcw, fcb, out);
}

// Round 7
// 1216.079 us; speedup vs baseline: 3.5141x; 1.4165x over previous
//
#include <hip/hip_runtime.h>
#include <hip/hip_bf16.h>

// MultiGAT on MI355X — round 6: resubmit of round-4 (repeated GPUAcquisitionTimeout;
// attn-MFMA rewrite still unmeasured — holding the kernel fixed until measured).
//  r1: MLP head -> grid-parallel GEMVs (measured good).
//  r2/r3: projection GEMM on MFMA via split-bf16 3-pass (measured: 1723us total).
//  r4: attn_active (985us, VALUBusy 29%, MfmaUtil 0, 7.6e7 bank-conflicts) -> MFMA:
//      - transpose_compact: qk -> qkT[gb][col][activeRank] bf16 (once, layer 1)
//      - attn kernel: V staged k-contiguous into XOR-chunk-swizzled LDS,
//        e = exp(tanh(sq+sk))-1 computed in B-fragment registers (z=Eq*Ek form),
//        P.V on mfma_f32_16x16x32_bf16, D[d][q] epilogue = float4 row stores.
//
// Math restructuring vs reference (exact up to fp reassociation):
//  - MASK_FILL = -1e-8 => exp(-1e-8) == 1.0f in fp32. softmax:
//      active q:  numer[d] = S_all[d] + sum_{act k} (exp(tanh(sq+sk))-1)*qk[k,d]
//                 denom    = 2048 + sum_{act k} (exp(tanh(..))-1)
//      masked q:  uniform attn -> hid = tanh(S_all/2048)
//  - Output uses only row N-1 after layer 2, so layer-2 attention is 1 q-row.

#define BB 4
#define NP 2047
#define NN 2048
#define DD 768
#define HH 6
#define DHH 128
#define FHH 768
#define NCC 4

typedef __attribute__((ext_vector_type(8))) short bf16x8;
typedef __attribute__((ext_vector_type(4))) float f32x4;

__device__ __forceinline__ float fast_tanh(float x) {
    float e = __expf(2.0f * x);
    return 1.0f - 2.0f / (e + 1.0f);
}

__device__ __forceinline__ float waveReduce(float v) {
#pragma unroll
    for (int off = 32; off; off >>= 1) v += __shfl_down(v, off);
    return v;
}

__device__ __forceinline__ unsigned short f2bf(float x) {   // RNE
    unsigned int u = __float_as_uint(x);
    unsigned int r = u + 0x7FFFu + ((u >> 16) & 1u);
    return (unsigned short)(r >> 16);
}
__device__ __forceinline__ float bf2f(unsigned short h) {
    return __uint_as_float((unsigned int)h << 16);
}

// ---------------------------------------------------------------- mask compaction
__global__ void mask_compact(const float* __restrict__ p_mask,
                             int* __restrict__ actList, int* __restrict__ inactList,
                             int* __restrict__ counts) {
    const int b = blockIdx.x;
    const int lane = threadIdx.x;           // blockDim = 64 (one wave)
    int nA = 0, nI = 0;
    for (int base = 0; base < NN; base += 64) {
        int i = base + lane;
        bool act = (i < NP) ? (p_mask[b * NP + i] > 0.0f) : true;
        unsigned long long mAct = __ballot(act);
        unsigned long long below = (1ull << lane) - 1ull;
        int pa = __popcll(mAct & below);
        int pi = __popcll((~mAct) & below);
        if (act) actList[b * NN + nA + pa] = i;
        else     inactList[b * NN + nI + pi] = i;
        int ca = __popcll(mAct);
        nA += ca;
        nI += 64 - ca;
    }
    if (lane == 0) { counts[b * 2] = nA; counts[b * 2 + 1] = nI; }
}

// ---------------------------------------------------------------- W split: fp32 -> bf16 hi/lo
__global__ __launch_bounds__(256) void split_w(const float* __restrict__ W,
                                               unsigned short* __restrict__ hi,
                                               unsigned short* __restrict__ lo) {
    size_t i = ((size_t)blockIdx.x * 256 + threadIdx.x) * 4;
    float4 v = *(const float4*)(W + i);
    unsigned short h0 = f2bf(v.x), h1 = f2bf(v.y), h2 = f2bf(v.z), h3 = f2bf(v.w);
    unsigned short l0 = f2bf(v.x - bf2f(h0)), l1 = f2bf(v.y - bf2f(h1));
    unsigned short l2 = f2bf(v.z - bf2f(h2)), l3 = f2bf(v.w - bf2f(h3));
    uint2 hw, lw;
    hw.x = (unsigned)h0 | ((unsigned)h1 << 16); hw.y = (unsigned)h2 | ((unsigned)h3 << 16);
    lw.x = (unsigned)l0 | ((unsigned)l1 << 16); lw.y = (unsigned)l2 | ((unsigned)l3 << 16);
    *(uint2*)(hi + i) = hw;
    *(uint2*)(lo + i) = lw;
}

// ---------------------------------------------------------------- qk = feat @ W^T (MFMA, split-bf16)
#define LDK 40
__global__ __launch_bounds__(256, 2) void gemm_qk_mfma(
    const float* __restrict__ feature, const float* __restrict__ c_node,
    const float* __restrict__ feat1, const unsigned short* __restrict__ Whi,
    const unsigned short* __restrict__ Wlo, float* __restrict__ qkOut,
    const int layer) {
    const int nt = blockIdx.x;   // 0..5   e-tile
    const int mt = blockIdx.y;   // 0..15  n-tile
    const int gb = blockIdx.z;   // g*4+b
    const int g = gb >> 2, b = gb & 3;
    const int t = threadIdx.x;

    __shared__ unsigned short Ahi[128][LDK], Alo[128][LDK];
    __shared__ unsigned short Bhi[128][LDK], Blo[128][LDK];

    const int srow = t >> 1;
    const int skq = (t & 1) * 16;
    const float* Arow;
    if (layer == 0) {
        int grow = mt * 128 + srow;
        Arow = (grow < NP) ? feature + ((size_t)b * NP + grow) * DD
                           : c_node + (size_t)b * DD;
    } else {
        Arow = feat1 + ((size_t)gb * NN + mt * 128 + srow) * DD;
    }
    const unsigned short* BrowH = Whi + ((size_t)g * DD + nt * 128 + srow) * DD;
    const unsigned short* BrowL = Wlo + ((size_t)g * DD + nt * 128 + srow) * DD;

    const int wv = t >> 6, lane = t & 63;
    const int wr = wv >> 1, wc = wv & 1;
    const int fr = lane & 15, kg = lane >> 4;

    f32x4 acc[4][4] = {};

    for (int k0 = 0; k0 < DD; k0 += 32) {
        float af[16];
        *(float4*)(af + 0)  = *(const float4*)(Arow + k0 + skq + 0);
        *(float4*)(af + 4)  = *(const float4*)(Arow + k0 + skq + 4);
        *(float4*)(af + 8)  = *(const float4*)(Arow + k0 + skq + 8);
        *(float4*)(af + 12) = *(const float4*)(Arow + k0 + skq + 12);
        uint4 bh0 = *(const uint4*)(BrowH + k0 + skq);
        uint4 bh1 = *(const uint4*)(BrowH + k0 + skq + 8);
        uint4 bl0 = *(const uint4*)(BrowL + k0 + skq);
        uint4 bl1 = *(const uint4*)(BrowL + k0 + skq + 8);

        __syncthreads();

        unsigned int hiw[8], low[8];
#pragma unroll
        for (int p = 0; p < 8; p++) {
            float x0 = af[2 * p], x1 = af[2 * p + 1];
            unsigned short h0 = f2bf(x0), h1 = f2bf(x1);
            unsigned short l0 = f2bf(x0 - bf2f(h0)), l1 = f2bf(x1 - bf2f(h1));
            hiw[p] = (unsigned)h0 | ((unsigned)h1 << 16);
            low[p] = (unsigned)l0 | ((unsigned)l1 << 16);
        }
        *(uint4*)&Ahi[srow][skq + 0] = make_uint4(hiw[0], hiw[1], hiw[2], hiw[3]);
        *(uint4*)&Ahi[srow][skq + 8] = make_uint4(hiw[4], hiw[5], hiw[6], hiw[7]);
        *(uint4*)&Alo[srow][skq + 0] = make_uint4(low[0], low[1], low[2], low[3]);
        *(uint4*)&Alo[srow][skq + 8] = make_uint4(low[4], low[5], low[6], low[7]);
        *(uint4*)&Bhi[srow][skq + 0] = bh0;
        *(uint4*)&Bhi[srow][skq + 8] = bh1;
        *(uint4*)&Blo[srow][skq + 0] = bl0;
        *(uint4*)&Blo[srow][skq + 8] = bl1;

        __syncthreads();

        bf16x8 bh[4], bl[4];
#pragma unroll
        for (int j = 0; j < 4; j++) {
            int row = wc * 64 + j * 16 + fr;
            bh[j] = *(const bf16x8*)&Bhi[row][kg * 8];
            bl[j] = *(const bf16x8*)&Blo[row][kg * 8];
        }
#pragma unroll
        for (int i = 0; i < 4; i++) {
            int row = wr * 64 + i * 16 + fr;
            bf16x8 ah = *(const bf16x8*)&Ahi[row][kg * 8];
            bf16x8 al = *(const bf16x8*)&Alo[row][kg * 8];
#pragma unroll
            for (int j = 0; j < 4; j++) {
                acc[i][j] = __builtin_amdgcn_mfma_f32_16x16x32_bf16(ah, bh[j], acc[i][j], 0, 0, 0);
                acc[i][j] = __builtin_amdgcn_mfma_f32_16x16x32_bf16(ah, bl[j], acc[i][j], 0, 0, 0);
                acc[i][j] = __builtin_amdgcn_mfma_f32_16x16x32_bf16(al, bh[j], acc[i][j], 0, 0, 0);
            }
        }
    }

    float* outB = qkOut + (size_t)gb * NN * DD;
#pragma unroll
    for (int i = 0; i < 4; i++) {
#pragma unroll
        for (int j = 0; j < 4; j++) {
            int rbase = mt * 128 + wr * 64 + i * 16 + kg * 4;
            int cbase = nt * 128 + wc * 64 + j * 16 + fr;
#pragma unroll
            for (int r = 0; r < 4; r++)
                outB[(size_t)(rbase + r) * DD + cbase] = acc[i][j][r];
        }
    }
}

// ---------------------------------------------------------------- sq, sk per row
__global__ __launch_bounds__(256) void sqsk(
    const float* __restrict__ qk, const float* __restrict__ attn_w,
    float* __restrict__ sq, float* __restrict__ sk) {
    const int gb = blockIdx.y, g = gb >> 2;
    const int w = threadIdx.x >> 6, lane = threadIdx.x & 63;
    const int n = blockIdx.x * 4 + w;
    const float* row = qk + ((size_t)gb * NN + n) * DD;
    const float* aw = attn_w + (size_t)g * HH * 2 * DHH;
#pragma unroll
    for (int h = 0; h < HH; h++) {
        float2 v = *(const float2*)(row + h * DHH + lane * 2);
        float q = v.x * aw[h * 256 + lane * 2] + v.y * aw[h * 256 + lane * 2 + 1];
        float k2 = v.x * aw[h * 256 + 128 + lane * 2] + v.y * aw[h * 256 + 128 + lane * 2 + 1];
        q = waveReduce(q);
        k2 = waveReduce(k2);
        if (lane == 0) {
            sq[((size_t)gb * NN + n) * HH + h] = q;
            sk[((size_t)gb * NN + n) * HH + h] = k2;
        }
    }
}

// ---------------------------------------------------------------- column sums of qk
__global__ __launch_bounds__(256) void colsum_part(const float* __restrict__ qk,
                                                   float* __restrict__ S_part) {
    const int gb = blockIdx.y;
    const int d = blockIdx.x * 256 + threadIdx.x;
    const int ch = blockIdx.z;
    const float* p = qk + ((size_t)gb * NN + (size_t)ch * 256) * DD + d;
    float s0 = 0, s1 = 0, s2 = 0, s3 = 0;
    for (int n = 0; n < 256; n += 4) {
        s0 += p[0];
        s1 += p[(size_t)DD];
        s2 += p[(size_t)2 * DD];
        s3 += p[(size_t)3 * DD];
        p += (size_t)4 * DD;
    }
    S_part[((size_t)gb * 8 + ch) * DD + d] = ((s0 + s1) + (s2 + s3));
}

__global__ __launch_bounds__(256) void finishS(const float* __restrict__ S_part,
                                               float* __restrict__ S_all,
                                               float* __restrict__ hidU) {
    const int gb = blockIdx.y;
    const int d = blockIdx.x * 256 + threadIdx.x;
    float s = 0;
#pragma unroll
    for (int c = 0; c < 8; c++) s += S_part[((size_t)gb * 8 + c) * DD + d];
    S_all[(size_t)gb * DD + d] = s;
    hidU[(size_t)gb * DD + d] = fast_tanh(s * (1.0f / 2048.0f));
}

// ---------------------------------------------------------------- masked-q rows (layer 1)
__global__ __launch_bounds__(256) void update_inactive(
    const float* __restrict__ feature, const float* __restrict__ c_node,
    const float* __restrict__ hidU, const int* __restrict__ inactList,
    const int* __restrict__ counts, float* __restrict__ feat1) {
    const int gb = blockIdx.y, b = gb & 3;
    const int idx = blockIdx.x;
    if (idx >= counts[b * 2 + 1]) return;
    const int n = inactList[b * NN + idx];
    const float* src = (n < NP) ? feature + ((size_t)b * NP + n) * DD
                                : c_node + (size_t)b * DD;
    const float* hu = hidU + (size_t)gb * DD;
    float* dst = feat1 + ((size_t)gb * NN + n) * DD;
    for (int d = threadIdx.x; d < DD; d += 256) dst[d] = src[d] + hu[d];
}

// ---------------------------------------------------------------- qk -> qkT (bf16, active-compacted, transposed)
// qkT[gb][col][j] = bf16(qk[actList[j]][col]), col = h*128+d, j k-contiguous.
__global__ __launch_bounds__(256) void transpose_compact(
    const float* __restrict__ qk, const int* __restrict__ actList,
    const int* __restrict__ counts, unsigned short* __restrict__ qkT) {
    const int gb = blockIdx.z, b = gb & 3;
    const int h = blockIdx.y;
    const int jt = blockIdx.x;
    const int nAct = counts[b * 2];
    if (jt * 64 >= nAct) return;

    __shared__ unsigned short T[64][130];   // [j][d], pad 130 -> 2-way write banks
    const int t = threadIdx.x;
    const int jr = t >> 2, dseg = t & 3;
    int jj = jt * 64 + jr;
    int kn = actList[b * NN + (jj < nAct ? jj : nAct - 1)];
    const float* srow = qk + ((size_t)gb * NN + kn) * DD + h * DHH + dseg * 32;
#pragma unroll
    for (int i = 0; i < 8; i++) {
        float4 v = *(const float4*)(srow + i * 4);
        int d = dseg * 32 + i * 4;
        unsigned int w0 = (unsigned)f2bf(v.x) | ((unsigned)f2bf(v.y) << 16);
        unsigned int w1 = (unsigned)f2bf(v.z) | ((unsigned)f2bf(v.w) << 16);
        *(unsigned int*)&T[jr][d] = w0;
        *(unsigned int*)&T[jr][d + 2] = w1;
    }
    __syncthreads();
    const int dd = t >> 1, jh = t & 1;
    unsigned short* orow = qkT + ((size_t)gb * DD + h * DHH + dd) * NN + jt * 64 + jh * 32;
#pragma unroll
    for (int i = 0; i < 4; i++) {
        unsigned short vs[8];
#pragma unroll
        for (int j2 = 0; j2 < 8; j2++) vs[j2] = T[jh * 32 + i * 8 + j2][dd];
        uint4 o;
        o.x = (unsigned)vs[0] | ((unsigned)vs[1] << 16);
        o.y = (unsigned)vs[2] | ((unsigned)vs[3] << 16);
        o.z = (unsigned)vs[4] | ((unsigned)vs[5] << 16);
        o.w = (unsigned)vs[6] | ((unsigned)vs[7] << 16);
        *(uint4*)(orow + i * 8) = o;
    }
}

// ---------------------------------------------------------------- active-q attention (layer 1, MFMA)
// Block: (qt, h, gb): 64 q x 128 d. D[d][q] = sum_k V_t[d][k] * e[q][k].
// A = V (from swizzled LDS), B = e (in-register). Wave wv owns q-cols wv*16..+16.
__global__ __launch_bounds__(256) void attn_active_mfma(
    const unsigned short* __restrict__ qkT, const float* __restrict__ sq,
    const float* __restrict__ sk, const float* __restrict__ S_all,
    const float* __restrict__ feature, const float* __restrict__ c_node,
    const int* __restrict__ actList, const int* __restrict__ counts,
    float* __restrict__ feat1) {
    const int gb = blockIdx.z, b = gb & 3;
    const int h = blockIdx.y;
    const int qt = blockIdx.x;
    const int nAct = counts[b * 2];
    if (qt * 64 >= nAct) return;

    __shared__ unsigned short Vt[128][64];   // [d][k] bf16, 16B-chunk XOR-swizzled
    __shared__ float Ek_s[64];
    __shared__ float Eq_s[64];
    __shared__ int qIdx[64];

    const int t = threadIdx.x;
    const int wv = t >> 6, lane = t & 63;
    const int fr = lane & 15, kg = lane >> 4;
    const int myq = wv * 16 + fr;            // this lane's q (B-frag col)

    if (t < 64) {
        int jj = qt * 64 + t;
        int qn = actList[b * NN + (jj < nAct ? jj : nAct - 1)];
        qIdx[t] = (jj < nAct) ? qn : -1;
        Eq_s[t] = __expf(2.0f * sq[((size_t)gb * NN + qn) * HH + h]);
    }

    const int sd = t >> 1, sh = t & 1;       // staging: row d, k-half
    const unsigned short* Trow = qkT + ((size_t)gb * DD + h * DHH + sd) * NN;

    f32x4 acc[8] = {};
    float dsum = 0.0f;
    const int nTiles = (nAct + 63) >> 6;

    for (int kt = 0; kt < nTiles; kt++) {
        uint4 vld[4];
        const unsigned short* src = Trow + kt * 64 + sh * 32;
#pragma unroll
        for (int i = 0; i < 4; i++) vld[i] = *(const uint4*)(src + i * 8);
        float ekv = 0.0f;
        if (t < 64) {
            int jk = kt * 64 + t;
            int kn2 = actList[b * NN + (jk < nAct ? jk : nAct - 1)];
            ekv = __expf(2.0f * sk[((size_t)gb * NN + kn2) * HH + h]);
        }
        __syncthreads();                     // prior tile's LDS reads complete
#pragma unroll
        for (int i = 0; i < 4; i++) {
            int cs = (sh * 4 + i) ^ (sd & 7);
            *(uint4*)&Vt[sd][cs * 8] = vld[i];
        }
        if (t < 64) Ek_s[t] = ekv;
        __syncthreads();

        // e B-fragments in registers: lane holds e[q=myq][k = ksub*32+kg*8+j]
        const float myEq = Eq_s[myq];
        bf16x8 ef[2];
#pragma unroll
        for (int ksub = 0; ksub < 2; ksub++) {
            union { unsigned int u[4]; bf16x8 v; } pk;
#pragma unroll
            for (int jp = 0; jp < 4; jp++) {
                unsigned short e2[2];
#pragma unroll
                for (int q2 = 0; q2 < 2; q2++) {
                    int kl = ksub * 32 + kg * 8 + jp * 2 + q2;
                    float z = myEq * Ek_s[kl];
                    float r = __builtin_amdgcn_rcpf(1.0f + z);
                    float th = 1.0f - 2.0f * r;            // tanh(sq+sk)
                    float e = __expf(th) - 1.0f;
                    e = (kt * 64 + kl < nAct) ? e : 0.0f;
                    dsum += e;
                    e2[q2] = f2bf(e);
                }
                pk.u[jp] = (unsigned)e2[0] | ((unsigned)e2[1] << 16);
            }
            ef[ksub] = pk.v;
        }

        // A = V fragments (row d = dt*16+fr, k contiguous), MFMA
#pragma unroll
        for (int dt = 0; dt < 8; dt++) {
            int d = dt * 16 + fr;
#pragma unroll
            for (int ksub = 0; ksub < 2; ksub++) {
                int cs = (ksub * 4 + kg) ^ (fr & 7);
                bf16x8 va = *(const bf16x8*)&Vt[d][cs * 8];
                acc[dt] = __builtin_amdgcn_mfma_f32_16x16x32_bf16(va, ef[ksub], acc[dt], 0, 0, 0);
            }
        }
    }

    // dsum: reduce over the 4 kg-groups sharing myq
    dsum += __shfl_xor(dsum, 16);
    dsum += __shfl_xor(dsum, 32);
    const float rden = 1.0f / (2048.0f + dsum);

    const int qn = qIdx[myq];
    if (qn >= 0) {
        const float* res = (qn < NP) ? feature + ((size_t)b * NP + qn) * DD + h * DHH
                                     : c_node + (size_t)b * DD + h * DHH;
        float* dst = feat1 + ((size_t)gb * NN + qn) * DD + h * DHH;
        const float* Sp = S_all + (size_t)gb * DD + h * DHH;
#pragma unroll
        for (int dt = 0; dt < 8; dt++) {
            int d0 = dt * 16 + kg * 4;       // C-layout: row = kg*4+reg, col = fr
            float4 sv = *(const float4*)(Sp + d0);
            float4 rv = *(const float4*)(res + d0);
            float4 o;
            o.x = rv.x + fast_tanh((acc[dt][0] + sv.x) * rden);
            o.y = rv.y + fast_tanh((acc[dt][1] + sv.y) * rden);
            o.z = rv.z + fast_tanh((acc[dt][2] + sv.z) * rden);
            o.w = rv.w + fast_tanh((acc[dt][3] + sv.w) * rden);
            *(float4*)(dst + d0) = o;
        }
    }
}

// ---------------------------------------------------------------- layer-2 attention, q = N-1 only
__global__ __launch_bounds__(128) void attn_final(
    const float* __restrict__ qk, const float* __restrict__ sq,
    const float* __restrict__ sk, const float* __restrict__ S_all,
    const float* __restrict__ feat1, const int* __restrict__ actList,
    const int* __restrict__ counts, float* __restrict__ gout) {
    const int h = blockIdx.x;
    const int gb = blockIdx.y, b = gb & 3;
    const int t = threadIdx.x;
    const int nAct = counts[b * 2];
    const float my_sq = sq[((size_t)gb * NN + (NN - 1)) * HH + h];
    float acc = 0.0f, wsum = 0.0f;
    for (int j = 0; j < nAct; j++) {
        int k = actList[b * NN + j];
        float e = __expf(fast_tanh(my_sq + sk[((size_t)gb * NN + k) * HH + h])) - 1.0f;
        acc = fmaf(e, qk[((size_t)gb * NN + k) * DD + h * DHH + t], acc);
        wsum += e;
    }
    float numer = acc + S_all[(size_t)gb * DD + h * DHH + t];
    float denom = 2048.0f + wsum;
    float hid = fast_tanh(numer / denom);
    gout[(size_t)gb * DD + h * DHH + t] =
        feat1[((size_t)gb * NN + (NN - 1)) * DD + h * DHH + t] + hid;
}

// ---------------------------------------------------------------- MLP: grid-parallel GEMV
__global__ __launch_bounds__(256) void mlp_gemv(
    const float* __restrict__ xin, const float* __restrict__ w,
    const float* __restrict__ bias, float* __restrict__ yout) {
    const int gb = blockIdx.y;
    const int wv = threadIdx.x >> 6, lane = threadIdx.x & 63;
    const int f = blockIdx.x * 4 + wv;
    const float* row = w + (size_t)f * FHH;
    const float* x = xin + (size_t)gb * FHH;
    float s = 0.0f;
#pragma unroll
    for (int d = lane * 4; d < FHH; d += 256) {
        float4 rv = *(const float4*)(row + d);
        float4 xv = *(const float4*)(x + d);
        s += rv.x * xv.x + rv.y * xv.y + rv.z * xv.z + rv.w * xv.w;
    }
    s = waveReduce(s);
    if (lane == 0) yout[(size_t)gb * FHH + f] = fmaxf(s + bias[f], 0.0f);
}

__global__ __launch_bounds__(256) void fc_out(
    const float* __restrict__ x2, const float* __restrict__ fcw,
    const float* __restrict__ fcb, float* __restrict__ out) {
    const int gb = blockIdx.x, g = gb >> 2, b = gb & 3;
    const int wv = threadIdx.x >> 6, lane = threadIdx.x & 63;
    const float* row = fcw + ((size_t)g * NCC + wv) * FHH;
    const float* x = x2 + (size_t)gb * FHH;
    float s = 0.0f;
#pragma unroll
    for (int d = lane * 4; d < FHH; d += 256) {
        float4 rv = *(const float4*)(row + d);
        float4 xv = *(const float4*)(x + d);
        s += rv.x * xv.x + rv.y * xv.y + rv.z * xv.z + rv.w * xv.w;
    }
    s = waveReduce(s);
    if (lane == 0) out[g * (BB * NCC) + b * NCC + wv] = s + fcb[g * NCC + wv];
}

extern "C" void kernel_launch(void* const* d_in, const int* in_sizes, int n_in,
                              void* d_out, int out_size, void* d_ws, size_t ws_size,
                              hipStream_t stream) {
    const float* p_mask  = (const float*)d_in[0];
    const float* feature = (const float*)d_in[1];
    const float* c_node  = (const float*)d_in[2];
    const float* W_gat   = (const float*)d_in[3];
    const float* attn_w  = (const float*)d_in[4];
    const float* w0      = (const float*)d_in[5];
    const float* b0      = (const float*)d_in[6];
    const float* w1      = (const float*)d_in[7];
    const float* b1      = (const float*)d_in[8];
    const float* fcw     = (const float*)d_in[9];
    const float* fcb     = (const float*)d_in[10];
    float* out = (float*)d_out;

    // workspace carve-up (~263 MB)
    float* fw = (float*)d_ws;
    size_t off = 0;
    float* feat1  = fw + off; off += (size_t)16 * NN * DD;
    float* qk     = fw + off; off += (size_t)16 * NN * DD;
    float* sq     = fw + off; off += (size_t)16 * NN * HH;
    float* sk     = fw + off; off += (size_t)16 * NN * HH;
    float* S_part = fw + off; off += (size_t)16 * 8 * DD;
    float* S_all  = fw + off; off += (size_t)16 * DD;
    float* hidU   = fw + off; off += (size_t)16 * DD;
    float* gout   = fw + off; off += (size_t)16 * DD;
    float* x1     = fw + off; off += (size_t)16 * FHH;
    float* x2     = fw + off; off += (size_t)16 * FHH;
    int* actList   = (int*)(fw + off); off += (size_t)BB * NN;
    int* inactList = (int*)(fw + off); off += (size_t)BB * NN;
    int* counts    = (int*)(fw + off); off += 16;
    unsigned short* Whi = (unsigned short*)(fw + off); off += (size_t)4 * DD * DD / 2;
    unsigned short* Wlo = (unsigned short*)(fw + off); off += (size_t)4 * DD * DD / 2;
    unsigned short* qkT = (unsigned short*)(fw + off); off += (size_t)16 * DD * NN / 2;

    mask_compact<<<dim3(BB), dim3(64), 0, stream>>>(p_mask, actList, inactList, counts);
    split_w<<<dim3(4 * DD * DD / 1024), dim3(256), 0, stream>>>(W_gat, Whi, Wlo);

    // -------- layer 1
    gemm_qk_mfma<<<dim3(6, 16, 16), dim3(256), 0, stream>>>(feature, c_node, feat1,
                                                            Whi, Wlo, qk, 0);
    sqsk<<<dim3(NN / 4, 16), dim3(256), 0, stream>>>(qk, attn_w, sq, sk);
    colsum_part<<<dim3(3, 16, 8), dim3(256), 0, stream>>>(qk, S_part);
    finishS<<<dim3(3, 16), dim3(256), 0, stream>>>(S_part, S_all, hidU);
    update_inactive<<<dim3(NN, 16), dim3(256), 0, stream>>>(feature, c_node, hidU,
                                                            inactList, counts, feat1);
    transpose_compact<<<dim3(32, HH, 16), dim3(256), 0, stream>>>(qk, actList, counts, qkT);
    attn_active_mfma<<<dim3(32, HH, 16), dim3(256), 0, stream>>>(qkT, sq, sk, S_all,
                                                                 feature, c_node,
                                                                 actList, counts, feat1);

    // -------- layer 2 (attention only needed for q = N-1)
    gemm_qk_mfma<<<dim3(6, 16, 16), dim3(256), 0, stream>>>(feature, c_node, feat1,
                                                            Whi, Wlo, qk, 1);
    sqsk<<<dim3(NN / 4, 16), dim3(256), 0, stream>>>(qk, attn_w, sq, sk);
    colsum_part<<<dim3(3, 16, 8), dim3(256), 0, stream>>>(qk, S_part);
    finishS<<<dim3(3, 16), dim3(256), 0, stream>>>(S_part, S_all, hidU);
    attn_final<<<dim3(HH, 16), dim3(128), 0, stream>>>(qk, sq, sk, S_all, feat1,
                                                       actList, counts, gout);

    // -------- MLP head (grid-parallel)
    mlp_gemv<<<dim3(FHH / 4, 16), dim3(256), 0, stream>>>(gout, w0, b0, x1);
    mlp_gemv<<<dim3(FHH / 4, 16), dim3(256), 0, stream>>>(x1, w1, b1, x2);
    fc_out<<<dim3(16), dim3(256), 0, stream>>>(x2, fcw, fcb, out);
}

// Round 10
// 1111.388 us; speedup vs baseline: 3.8451x; 1.0942x over previous
//
#include <hip/hip_runtime.h>
#include <hip/hip_bf16.h>

// MultiGAT on MI355X — round 9: resubmit of round-7 (repeated GPUAcquisitionTimeout;
// KT=128 + XCD-swizzle attn fix still unmeasured — holding kernel fixed).
//  r1: MLP head -> grid-parallel GEMVs.
//  r2/r3: projection GEMM on MFMA via split-bf16 3-pass.
//  r4/r6: attn_active -> MFMA (985 -> 375us, bank-conflicts 7.6e7 -> 0).
//  r7: attn latency fix: KT=128 staging (2x bytes in flight, half the
//      barriers) + bijective XCD swizzle (same-(h,gb) qt-blocks share one
//      XCD's L2 so the 512KB qkT panel stays resident).
//
// Math restructuring vs reference (exact up to fp reassociation):
//  - MASK_FILL = -1e-8 => exp(-1e-8) == 1.0f in fp32. softmax:
//      active q:  numer[d] = S_all[d] + sum_{act k} (exp(tanh(sq+sk))-1)*qk[k,d]
//                 denom    = 2048 + sum_{act k} (exp(tanh(..))-1)
//      masked q:  uniform attn -> hid = tanh(S_all/2048)
//  - Output uses only row N-1 after layer 2, so layer-2 attention is 1 q-row.

#define BB 4
#define NP 2047
#define NN 2048
#define DD 768
#define HH 6
#define DHH 128
#define FHH 768
#define NCC 4

typedef __attribute__((ext_vector_type(8))) short bf16x8;
typedef __attribute__((ext_vector_type(4))) float f32x4;

__device__ __forceinline__ float fast_tanh(float x) {
    float e = __expf(2.0f * x);
    return 1.0f - 2.0f / (e + 1.0f);
}

__device__ __forceinline__ float waveReduce(float v) {
#pragma unroll
    for (int off = 32; off; off >>= 1) v += __shfl_down(v, off);
    return v;
}

__device__ __forceinline__ unsigned short f2bf(float x) {   // RNE
    unsigned int u = __float_as_uint(x);
    unsigned int r = u + 0x7FFFu + ((u >> 16) & 1u);
    return (unsigned short)(r >> 16);
}
__device__ __forceinline__ float bf2f(unsigned short h) {
    return __uint_as_float((unsigned int)h << 16);
}

// ---------------------------------------------------------------- mask compaction
__global__ void mask_compact(const float* __restrict__ p_mask,
                             int* __restrict__ actList, int* __restrict__ inactList,
                             int* __restrict__ counts) {
    const int b = blockIdx.x;
    const int lane = threadIdx.x;           // blockDim = 64 (one wave)
    int nA = 0, nI = 0;
    for (int base = 0; base < NN; base += 64) {
        int i = base + lane;
        bool act = (i < NP) ? (p_mask[b * NP + i] > 0.0f) : true;
        unsigned long long mAct = __ballot(act);
        unsigned long long below = (1ull << lane) - 1ull;
        int pa = __popcll(mAct & below);
        int pi = __popcll((~mAct) & below);
        if (act) actList[b * NN + nA + pa] = i;
        else     inactList[b * NN + nI + pi] = i;
        int ca = __popcll(mAct);
        nA += ca;
        nI += 64 - ca;
    }
    if (lane == 0) { counts[b * 2] = nA; counts[b * 2 + 1] = nI; }
}

// ---------------------------------------------------------------- W split: fp32 -> bf16 hi/lo
__global__ __launch_bounds__(256) void split_w(const float* __restrict__ W,
                                               unsigned short* __restrict__ hi,
                                               unsigned short* __restrict__ lo) {
    size_t i = ((size_t)blockIdx.x * 256 + threadIdx.x) * 4;
    float4 v = *(const float4*)(W + i);
    unsigned short h0 = f2bf(v.x), h1 = f2bf(v.y), h2 = f2bf(v.z), h3 = f2bf(v.w);
    unsigned short l0 = f2bf(v.x - bf2f(h0)), l1 = f2bf(v.y - bf2f(h1));
    unsigned short l2 = f2bf(v.z - bf2f(h2)), l3 = f2bf(v.w - bf2f(h3));
    uint2 hw, lw;
    hw.x = (unsigned)h0 | ((unsigned)h1 << 16); hw.y = (unsigned)h2 | ((unsigned)h3 << 16);
    lw.x = (unsigned)l0 | ((unsigned)l1 << 16); lw.y = (unsigned)l2 | ((unsigned)l3 << 16);
    *(uint2*)(hi + i) = hw;
    *(uint2*)(lo + i) = lw;
}

// ---------------------------------------------------------------- qk = feat @ W^T (MFMA, split-bf16)
#define LDK 40
__global__ __launch_bounds__(256, 2) void gemm_qk_mfma(
    const float* __restrict__ feature, const float* __restrict__ c_node,
    const float* __restrict__ feat1, const unsigned short* __restrict__ Whi,
    const unsigned short* __restrict__ Wlo, float* __restrict__ qkOut,
    const int layer) {
    const int nt = blockIdx.x;   // 0..5   e-tile
    const int mt = blockIdx.y;   // 0..15  n-tile
    const int gb = blockIdx.z;   // g*4+b
    const int g = gb >> 2, b = gb & 3;
    const int t = threadIdx.x;

    __shared__ unsigned short Ahi[128][LDK], Alo[128][LDK];
    __shared__ unsigned short Bhi[128][LDK], Blo[128][LDK];

    const int srow = t >> 1;
    const int skq = (t & 1) * 16;
    const float* Arow;
    if (layer == 0) {
        int grow = mt * 128 + srow;
        Arow = (grow < NP) ? feature + ((size_t)b * NP + grow) * DD
                           : c_node + (size_t)b * DD;
    } else {
        Arow = feat1 + ((size_t)gb * NN + mt * 128 + srow) * DD;
    }
    const unsigned short* BrowH = Whi + ((size_t)g * DD + nt * 128 + srow) * DD;
    const unsigned short* BrowL = Wlo + ((size_t)g * DD + nt * 128 + srow) * DD;

    const int wv = t >> 6, lane = t & 63;
    const int wr = wv >> 1, wc = wv & 1;
    const int fr = lane & 15, kg = lane >> 4;

    f32x4 acc[4][4] = {};

    for (int k0 = 0; k0 < DD; k0 += 32) {
        float af[16];
        *(float4*)(af + 0)  = *(const float4*)(Arow + k0 + skq + 0);
        *(float4*)(af + 4)  = *(const float4*)(Arow + k0 + skq + 4);
        *(float4*)(af + 8)  = *(const float4*)(Arow + k0 + skq + 8);
        *(float4*)(af + 12) = *(const float4*)(Arow + k0 + skq + 12);
        uint4 bh0 = *(const uint4*)(BrowH + k0 + skq);
        uint4 bh1 = *(const uint4*)(BrowH + k0 + skq + 8);
        uint4 bl0 = *(const uint4*)(BrowL + k0 + skq);
        uint4 bl1 = *(const uint4*)(BrowL + k0 + skq + 8);

        __syncthreads();

        unsigned int hiw[8], low[8];
#pragma unroll
        for (int p = 0; p < 8; p++) {
            float x0 = af[2 * p], x1 = af[2 * p + 1];
            unsigned short h0 = f2bf(x0), h1 = f2bf(x1);
            unsigned short l0 = f2bf(x0 - bf2f(h0)), l1 = f2bf(x1 - bf2f(h1));
            hiw[p] = (unsigned)h0 | ((unsigned)h1 << 16);
            low[p] = (unsigned)l0 | ((unsigned)l1 << 16);
        }
        *(uint4*)&Ahi[srow][skq + 0] = make_uint4(hiw[0], hiw[1], hiw[2], hiw[3]);
        *(uint4*)&Ahi[srow][skq + 8] = make_uint4(hiw[4], hiw[5], hiw[6], hiw[7]);
        *(uint4*)&Alo[srow][skq + 0] = make_uint4(low[0], low[1], low[2], low[3]);
        *(uint4*)&Alo[srow][skq + 8] = make_uint4(low[4], low[5], low[6], low[7]);
        *(uint4*)&Bhi[srow][skq + 0] = bh0;
        *(uint4*)&Bhi[srow][skq + 8] = bh1;
        *(uint4*)&Blo[srow][skq + 0] = bl0;
        *(uint4*)&Blo[srow][skq + 8] = bl1;

        __syncthreads();

        bf16x8 bh[4], bl[4];
#pragma unroll
        for (int j = 0; j < 4; j++) {
            int row = wc * 64 + j * 16 + fr;
            bh[j] = *(const bf16x8*)&Bhi[row][kg * 8];
            bl[j] = *(const bf16x8*)&Blo[row][kg * 8];
        }
#pragma unroll
        for (int i = 0; i < 4; i++) {
            int row = wr * 64 + i * 16 + fr;
            bf16x8 ah = *(const bf16x8*)&Ahi[row][kg * 8];
            bf16x8 al = *(const bf16x8*)&Alo[row][kg * 8];
#pragma unroll
            for (int j = 0; j < 4; j++) {
                acc[i][j] = __builtin_amdgcn_mfma_f32_16x16x32_bf16(ah, bh[j], acc[i][j], 0, 0, 0);
                acc[i][j] = __builtin_amdgcn_mfma_f32_16x16x32_bf16(ah, bl[j], acc[i][j], 0, 0, 0);
                acc[i][j] = __builtin_amdgcn_mfma_f32_16x16x32_bf16(al, bh[j], acc[i][j], 0, 0, 0);
            }
        }
    }

    float* outB = qkOut + (size_t)gb * NN * DD;
#pragma unroll
    for (int i = 0; i < 4; i++) {
#pragma unroll
        for (int j = 0; j < 4; j++) {
            int rbase = mt * 128 + wr * 64 + i * 16 + kg * 4;
            int cbase = nt * 128 + wc * 64 + j * 16 + fr;
#pragma unroll
            for (int r = 0; r < 4; r++)
                outB[(size_t)(rbase + r) * DD + cbase] = acc[i][j][r];
        }
    }
}

// ---------------------------------------------------------------- sq, sk per row
__global__ __launch_bounds__(256) void sqsk(
    const float* __restrict__ qk, const float* __restrict__ attn_w,
    float* __restrict__ sq, float* __restrict__ sk) {
    const int gb = blockIdx.y, g = gb >> 2;
    const int w = threadIdx.x >> 6, lane = threadIdx.x & 63;
    const int n = blockIdx.x * 4 + w;
    const float* row = qk + ((size_t)gb * NN + n) * DD;
    const float* aw = attn_w + (size_t)g * HH * 2 * DHH;
#pragma unroll
    for (int h = 0; h < HH; h++) {
        float2 v = *(const float2*)(row + h * DHH + lane * 2);
        float q = v.x * aw[h * 256 + lane * 2] + v.y * aw[h * 256 + lane * 2 + 1];
        float k2 = v.x * aw[h * 256 + 128 + lane * 2] + v.y * aw[h * 256 + 128 + lane * 2 + 1];
        q = waveReduce(q);
        k2 = waveReduce(k2);
        if (lane == 0) {
            sq[((size_t)gb * NN + n) * HH + h] = q;
            sk[((size_t)gb * NN + n) * HH + h] = k2;
        }
    }
}

// ---------------------------------------------------------------- column sums of qk
__global__ __launch_bounds__(256) void colsum_part(const float* __restrict__ qk,
                                                   float* __restrict__ S_part) {
    const int gb = blockIdx.y;
    const int d = blockIdx.x * 256 + threadIdx.x;
    const int ch = blockIdx.z;
    const float* p = qk + ((size_t)gb * NN + (size_t)ch * 256) * DD + d;
    float s0 = 0, s1 = 0, s2 = 0, s3 = 0;
    for (int n = 0; n < 256; n += 4) {
        s0 += p[0];
        s1 += p[(size_t)DD];
        s2 += p[(size_t)2 * DD];
        s3 += p[(size_t)3 * DD];
        p += (size_t)4 * DD;
    }
    S_part[((size_t)gb * 8 + ch) * DD + d] = ((s0 + s1) + (s2 + s3));
}

__global__ __launch_bounds__(256) void finishS(const float* __restrict__ S_part,
                                               float* __restrict__ S_all,
                                               float* __restrict__ hidU) {
    const int gb = blockIdx.y;
    const int d = blockIdx.x * 256 + threadIdx.x;
    float s = 0;
#pragma unroll
    for (int c = 0; c < 8; c++) s += S_part[((size_t)gb * 8 + c) * DD + d];
    S_all[(size_t)gb * DD + d] = s;
    hidU[(size_t)gb * DD + d] = fast_tanh(s * (1.0f / 2048.0f));
}

// ---------------------------------------------------------------- masked-q rows (layer 1)
__global__ __launch_bounds__(256) void update_inactive(
    const float* __restrict__ feature, const float* __restrict__ c_node,
    const float* __restrict__ hidU, const int* __restrict__ inactList,
    const int* __restrict__ counts, float* __restrict__ feat1) {
    const int gb = blockIdx.y, b = gb & 3;
    const int idx = blockIdx.x;
    if (idx >= counts[b * 2 + 1]) return;
    const int n = inactList[b * NN + idx];
    const float* src = (n < NP) ? feature + ((size_t)b * NP + n) * DD
                                : c_node + (size_t)b * DD;
    const float* hu = hidU + (size_t)gb * DD;
    float* dst = feat1 + ((size_t)gb * NN + n) * DD;
    for (int d = threadIdx.x; d < DD; d += 256) dst[d] = src[d] + hu[d];
}

// ---------------------------------------------------------------- qk -> qkT (bf16, active-compacted, transposed)
// qkT[gb][col][j] = bf16(qk[actList[j]][col]), col = h*128+d, j k-contiguous.
__global__ __launch_bounds__(256) void transpose_compact(
    const float* __restrict__ qk, const int* __restrict__ actList,
    const int* __restrict__ counts, unsigned short* __restrict__ qkT) {
    const int gb = blockIdx.z, b = gb & 3;
    const int h = blockIdx.y;
    const int jt = blockIdx.x;
    const int nAct = counts[b * 2];
    if (jt * 64 >= nAct) return;

    __shared__ unsigned short T[64][130];   // [j][d], pad 130 -> 2-way write banks
    const int t = threadIdx.x;
    const int jr = t >> 2, dseg = t & 3;
    int jj = jt * 64 + jr;
    int kn = actList[b * NN + (jj < nAct ? jj : nAct - 1)];
    const float* srow = qk + ((size_t)gb * NN + kn) * DD + h * DHH + dseg * 32;
#pragma unroll
    for (int i = 0; i < 8; i++) {
        float4 v = *(const float4*)(srow + i * 4);
        int d = dseg * 32 + i * 4;
        unsigned int w0 = (unsigned)f2bf(v.x) | ((unsigned)f2bf(v.y) << 16);
        unsigned int w1 = (unsigned)f2bf(v.z) | ((unsigned)f2bf(v.w) << 16);
        *(unsigned int*)&T[jr][d] = w0;
        *(unsigned int*)&T[jr][d + 2] = w1;
    }
    __syncthreads();
    const int dd = t >> 1, jh = t & 1;
    unsigned short* orow = qkT + ((size_t)gb * DD + h * DHH + dd) * NN + jt * 64 + jh * 32;
#pragma unroll
    for (int i = 0; i < 4; i++) {
        unsigned short vs[8];
#pragma unroll
        for (int j2 = 0; j2 < 8; j2++) vs[j2] = T[jh * 32 + i * 8 + j2][dd];
        uint4 o;
        o.x = (unsigned)vs[0] | ((unsigned)vs[1] << 16);
        o.y = (unsigned)vs[2] | ((unsigned)vs[3] << 16);
        o.z = (unsigned)vs[4] | ((unsigned)vs[5] << 16);
        o.w = (unsigned)vs[6] | ((unsigned)vs[7] << 16);
        *(uint4*)(orow + i * 8) = o;
    }
}

// ---------------------------------------------------------------- active-q attention (layer 1, MFMA)
// Block: (qt, h, gb): 64 q x 128 d, KT=128 k per stage. XCD-swizzled block ids.
// D[d][q] = sum_k V_t[d][k] * e[q][k]. A = V (swizzled LDS), B = e (in-register).
__global__ __launch_bounds__(256) void attn_active_mfma(
    const unsigned short* __restrict__ qkT, const float* __restrict__ sq,
    const float* __restrict__ sk, const float* __restrict__ S_all,
    const float* __restrict__ feature, const float* __restrict__ c_node,
    const int* __restrict__ actList, const int* __restrict__ counts,
    float* __restrict__ feat1) {
    // XCD swizzle: nwg = 32*6*16 = 3072 (div by 8). fid%8 ~ XCD; give each XCD
    // contiguous (h,gb) panels so the 512KB qkT panel stays L2-resident.
    const int fid = blockIdx.x + 32 * (blockIdx.y + 6 * blockIdx.z);
    const int nfid = (fid & 7) * 384 + (fid >> 3);
    const int qt = nfid & 31;
    const int hg = nfid >> 5;
    const int h = hg % 6;
    const int gb = hg / 6;
    const int b = gb & 3;
    const int nAct = counts[b * 2];
    if (qt * 64 >= nAct) return;

    __shared__ unsigned short Vt[128][128];  // [d][k] bf16, 16B-chunk XOR-swizzled
    __shared__ float Ek_s[128];
    __shared__ float Eq_s[64];
    __shared__ int qIdx[64];

    const int t = threadIdx.x;
    const int wv = t >> 6, lane = t & 63;
    const int fr = lane & 15, kg = lane >> 4;
    const int myq = wv * 16 + fr;            // this lane's q (B-frag col)

    if (t < 64) {
        int jj = qt * 64 + t;
        int qn = actList[b * NN + (jj < nAct ? jj : nAct - 1)];
        qIdx[t] = (jj < nAct) ? qn : -1;
        Eq_s[t] = __expf(2.0f * sq[((size_t)gb * NN + qn) * HH + h]);
    }

    const int sd = t >> 1, sh = t & 1;       // staging: row d, k-half (64 each)
    const unsigned short* Trow = qkT + ((size_t)gb * DD + h * DHH + sd) * NN;

    f32x4 acc[8] = {};
    float dsum = 0.0f;
    const int nTiles = (nAct + 127) >> 7;

    for (int kt = 0; kt < nTiles; kt++) {
        uint4 vld[8];
        const unsigned short* src = Trow + kt * 128 + sh * 64;
#pragma unroll
        for (int i = 0; i < 8; i++) vld[i] = *(const uint4*)(src + i * 8);
        float ekv = 0.0f;
        if (t < 128) {
            int jk = kt * 128 + t;
            int kn2 = actList[b * NN + (jk < nAct ? jk : nAct - 1)];
            ekv = __expf(2.0f * sk[((size_t)gb * NN + kn2) * HH + h]);
        }
        __syncthreads();                     // prior tile's LDS reads complete
#pragma unroll
        for (int i = 0; i < 8; i++) {
            int cs = (sh * 8 + i) ^ (sd & 15);
            *(uint4*)&Vt[sd][cs * 8] = vld[i];
        }
        if (t < 128) Ek_s[t] = ekv;
        __syncthreads();

        // e B-fragments in registers: lane holds e[q=myq][k = ksub*32+kg*8+j]
        const float myEq = Eq_s[myq];
        bf16x8 ef[4];
#pragma unroll
        for (int ksub = 0; ksub < 4; ksub++) {
            union { unsigned int u[4]; bf16x8 v; } pk;
#pragma unroll
            for (int jp = 0; jp < 4; jp++) {
                unsigned short e2[2];
#pragma unroll
                for (int q2 = 0; q2 < 2; q2++) {
                    int kl = ksub * 32 + kg * 8 + jp * 2 + q2;
                    float z = myEq * Ek_s[kl];
                    float r = __builtin_amdgcn_rcpf(1.0f + z);
                    float th = 1.0f - 2.0f * r;            // tanh(sq+sk)
                    float e = __expf(th) - 1.0f;
                    e = (kt * 128 + kl < nAct) ? e : 0.0f;
                    dsum += e;
                    e2[q2] = f2bf(e);
                }
                pk.u[jp] = (unsigned)e2[0] | ((unsigned)e2[1] << 16);
            }
            ef[ksub] = pk.v;
        }

        // A = V fragments (row d = dt*16+fr, k contiguous), MFMA
#pragma unroll
        for (int dt = 0; dt < 8; dt++) {
            int d = dt * 16 + fr;
#pragma unroll
            for (int ksub = 0; ksub < 4; ksub++) {
                int cs = (ksub * 4 + kg) ^ fr;
                bf16x8 va = *(const bf16x8*)&Vt[d][cs * 8];
                acc[dt] = __builtin_amdgcn_mfma_f32_16x16x32_bf16(va, ef[ksub], acc[dt], 0, 0, 0);
            }
        }
    }

    // dsum: reduce over the 4 kg-groups sharing myq
    dsum += __shfl_xor(dsum, 16);
    dsum += __shfl_xor(dsum, 32);
    const float rden = 1.0f / (2048.0f + dsum);

    const int qn = qIdx[myq];
    if (qn >= 0) {
        const float* res = (qn < NP) ? feature + ((size_t)b * NP + qn) * DD + h * DHH
                                     : c_node + (size_t)b * DD + h * DHH;
        float* dst = feat1 + ((size_t)gb * NN + qn) * DD + h * DHH;
        const float* Sp = S_all + (size_t)gb * DD + h * DHH;
#pragma unroll
        for (int dt = 0; dt < 8; dt++) {
            int d0 = dt * 16 + kg * 4;       // C-layout: row = kg*4+reg, col = fr
            float4 sv = *(const float4*)(Sp + d0);
            float4 rv = *(const float4*)(res + d0);
            float4 o;
            o.x = rv.x + fast_tanh((acc[dt][0] + sv.x) * rden);
            o.y = rv.y + fast_tanh((acc[dt][1] + sv.y) * rden);
            o.z = rv.z + fast_tanh((acc[dt][2] + sv.z) * rden);
            o.w = rv.w + fast_tanh((acc[dt][3] + sv.w) * rden);
            *(float4*)(dst + d0) = o;
        }
    }
}

// ---------------------------------------------------------------- layer-2 attention, q = N-1 only
__global__ __launch_bounds__(128) void attn_final(
    const float* __restrict__ qk, const float* __restrict__ sq,
    const float* __restrict__ sk, const float* __restrict__ S_all,
    const float* __restrict__ feat1, const int* __restrict__ actList,
    const int* __restrict__ counts, float* __restrict__ gout) {
    const int h = blockIdx.x;
    const int gb = blockIdx.y, b = gb & 3;
    const int t = threadIdx.x;
    const int nAct = counts[b * 2];
    const float my_sq = sq[((size_t)gb * NN + (NN - 1)) * HH + h];
    float acc = 0.0f, wsum = 0.0f;
    for (int j = 0; j < nAct; j++) {
        int k = actList[b * NN + j];
        float e = __expf(fast_tanh(my_sq + sk[((size_t)gb * NN + k) * HH + h])) - 1.0f;
        acc = fmaf(e, qk[((size_t)gb * NN + k) * DD + h * DHH + t], acc);
        wsum += e;
    }
    float numer = acc + S_all[(size_t)gb * DD + h * DHH + t];
    float denom = 2048.0f + wsum;
    float hid = fast_tanh(numer / denom);
    gout[(size_t)gb * DD + h * DHH + t] =
        feat1[((size_t)gb * NN + (NN - 1)) * DD + h * DHH + t] + hid;
}

// ---------------------------------------------------------------- MLP: grid-parallel GEMV
__global__ __launch_bounds__(256) void mlp_gemv(
    const float* __restrict__ xin, const float* __restrict__ w,
    const float* __restrict__ bias, float* __restrict__ yout) {
    const int gb = blockIdx.y;
    const int wv = threadIdx.x >> 6, lane = threadIdx.x & 63;
    const int f = blockIdx.x * 4 + wv;
    const float* row = w + (size_t)f * FHH;
    const float* x = xin + (size_t)gb * FHH;
    float s = 0.0f;
#pragma unroll
    for (int d = lane * 4; d < FHH; d += 256) {
        float4 rv = *(const float4*)(row + d);
        float4 xv = *(const float4*)(x + d);
        s += rv.x * xv.x + rv.y * xv.y + rv.z * xv.z + rv.w * xv.w;
    }
    s = waveReduce(s);
    if (lane == 0) yout[(size_t)gb * FHH + f] = fmaxf(s + bias[f], 0.0f);
}

__global__ __launch_bounds__(256) void fc_out(
    const float* __restrict__ x2, const float* __restrict__ fcw,
    const float* __restrict__ fcb, float* __restrict__ out) {
    const int gb = blockIdx.x, g = gb >> 2, b = gb & 3;
    const int wv = threadIdx.x >> 6, lane = threadIdx.x & 63;
    const float* row = fcw + ((size_t)g * NCC + wv) * FHH;
    const float* x = x2 + (size_t)gb * FHH;
    float s = 0.0f;
#pragma unroll
    for (int d = lane * 4; d < FHH; d += 256) {
        float4 rv = *(const float4*)(row + d);
        float4 xv = *(const float4*)(x + d);
        s += rv.x * xv.x + rv.y * xv.y + rv.z * xv.z + rv.w * xv.w;
    }
    s = waveReduce(s);
    if (lane == 0) out[g * (BB * NCC) + b * NCC + wv] = s + fcb[g * NCC + wv];
}

extern "C" void kernel_launch(void* const* d_in, const int* in_sizes, int n_in,
                              void* d_out, int out_size, void* d_ws, size_t ws_size,
                              hipStream_t stream) {
    const float* p_mask  = (const float*)d_in[0];
    const float* feature = (const float*)d_in[1];
    const float* c_node  = (const float*)d_in[2];
    const float* W_gat   = (const float*)d_in[3];
    const float* attn_w  = (const float*)d_in[4];
    const float* w0      = (const float*)d_in[5];
    const float* b0      = (const float*)d_in[6];
    const float* w1      = (const float*)d_in[7];
    const float* b1      = (const float*)d_in[8];
    const float* fcw     = (const float*)d_in[9];
    const float* fcb     = (const float*)d_in[10];
    float* out = (float*)d_out;

    // workspace carve-up (~263 MB)
    float* fw = (float*)d_ws;
    size_t off = 0;
    float* feat1  = fw + off; off += (size_t)16 * NN * DD;
    float* qk     = fw + off; off += (size_t)16 * NN * DD;
    float* sq     = fw + off; off += (size_t)16 * NN * HH;
    float* sk     = fw + off; off += (size_t)16 * NN * HH;
    float* S_part = fw + off; off += (size_t)16 * 8 * DD;
    float* S_all  = fw + off; off += (size_t)16 * DD;
    float* hidU   = fw + off; off += (size_t)16 * DD;
    float* gout   = fw + off; off += (size_t)16 * DD;
    float* x1     = fw + off; off += (size_t)16 * FHH;
    float* x2     = fw + off; off += (size_t)16 * FHH;
    int* actList   = (int*)(fw + off); off += (size_t)BB * NN;
    int* inactList = (int*)(fw + off); off += (size_t)BB * NN;
    int* counts    = (int*)(fw + off); off += 16;
    unsigned short* Whi = (unsigned short*)(fw + off); off += (size_t)4 * DD * DD / 2;
    unsigned short* Wlo = (unsigned short*)(fw + off); off += (size_t)4 * DD * DD / 2;
    unsigned short* qkT = (unsigned short*)(fw + off); off += (size_t)16 * DD * NN / 2;

    mask_compact<<<dim3(BB), dim3(64), 0, stream>>>(p_mask, actList, inactList, counts);
    split_w<<<dim3(4 * DD * DD / 1024), dim3(256), 0, stream>>>(W_gat, Whi, Wlo);

    // -------- layer 1
    gemm_qk_mfma<<<dim3(6, 16, 16), dim3(256), 0, stream>>>(feature, c_node, feat1,
                                                            Whi, Wlo, qk, 0);
    sqsk<<<dim3(NN / 4, 16), dim3(256), 0, stream>>>(qk, attn_w, sq, sk);
    colsum_part<<<dim3(3, 16, 8), dim3(256), 0, stream>>>(qk, S_part);
    finishS<<<dim3(3, 16), dim3(256), 0, stream>>>(S_part, S_all, hidU);
    update_inactive<<<dim3(NN, 16), dim3(256), 0, stream>>>(feature, c_node, hidU,
                                                            inactList, counts, feat1);
    transpose_compact<<<dim3(32, HH, 16), dim3(256), 0, stream>>>(qk, actList, counts, qkT);
    attn_active_mfma<<<dim3(32, HH, 16), dim3(256), 0, stream>>>(qkT, sq, sk, S_all,
                                                                 feature, c_node,
                                                                 actList, counts, feat1);

    // -------- layer 2 (attention only needed for q = N-1)
    gemm_qk_mfma<<<dim3(6, 16, 16), dim3(256), 0, stream>>>(feature, c_node, feat1,
                                                            Whi, Wlo, qk, 1);
    sqsk<<<dim3(NN / 4, 16), dim3(256), 0, stream>>>(qk, attn_w, sq, sk);
    colsum_part<<<dim3(3, 16, 8), dim3(256), 0, stream>>>(qk, S_part);
    finishS<<<dim3(3, 16), dim3(256), 0, stream>>>(S_part, S_all, hidU);
    attn_final<<<dim3(HH, 16), dim3(128), 0, stream>>>(qk, sq, sk, S_all, feat1,
                                                       actList, counts, gout);

    // -------- MLP head (grid-parallel)
    mlp_gemv<<<dim3(FHH / 4, 16), dim3(256), 0, stream>>>(gout, w0, b0, x1);
    mlp_gemv<<<dim3(FHH / 4, 16), dim3(256), 0, stream>>>(x1, w1, b1, x2);
    fc_out<<<dim3(16), dim3(256), 0, stream>>>(x2, fcw, fcb, out);
}

// Round 11
// 826.668 us; speedup vs baseline: 5.1694x; 1.3444x over previous
//
#include <hip/hip_runtime.h>
#include <hip/hip_bf16.h>

// MultiGAT on MI355X — round 10: attn_final latency fix.
//  r1: MLP head -> grid-parallel GEMVs.
//  r2/r3: projection GEMM on MFMA via split-bf16 3-pass.
//  r4/r6: attn_active -> MFMA (985 -> 375us, bank-conflicts 7.6e7 -> 0).
//  r7: attn KT=128 + XCD swizzle (total 1216 -> 1111us).
//  r10: attn_final (342us, VALUBusy 2.6%, occ 2.2% — 1024-iter dependent-chain
//       loop per thread) -> two-phase: j-parallel e into LDS, then
//       independent-address weighted sum (unroll-4, loads pipeline).
//
// Math restructuring vs reference (exact up to fp reassociation):
//  - MASK_FILL = -1e-8 => exp(-1e-8) == 1.0f in fp32. softmax:
//      active q:  numer[d] = S_all[d] + sum_{act k} (exp(tanh(sq+sk))-1)*qk[k,d]
//                 denom    = 2048 + sum_{act k} (exp(tanh(..))-1)
//      masked q:  uniform attn -> hid = tanh(S_all/2048)
//  - Output uses only row N-1 after layer 2, so layer-2 attention is 1 q-row.

#define BB 4
#define NP 2047
#define NN 2048
#define DD 768
#define HH 6
#define DHH 128
#define FHH 768
#define NCC 4

typedef __attribute__((ext_vector_type(8))) short bf16x8;
typedef __attribute__((ext_vector_type(4))) float f32x4;

__device__ __forceinline__ float fast_tanh(float x) {
    float e = __expf(2.0f * x);
    return 1.0f - 2.0f / (e + 1.0f);
}

__device__ __forceinline__ float waveReduce(float v) {
#pragma unroll
    for (int off = 32; off; off >>= 1) v += __shfl_down(v, off);
    return v;
}

__device__ __forceinline__ unsigned short f2bf(float x) {   // RNE
    unsigned int u = __float_as_uint(x);
    unsigned int r = u + 0x7FFFu + ((u >> 16) & 1u);
    return (unsigned short)(r >> 16);
}
__device__ __forceinline__ float bf2f(unsigned short h) {
    return __uint_as_float((unsigned int)h << 16);
}

// ---------------------------------------------------------------- mask compaction
__global__ void mask_compact(const float* __restrict__ p_mask,
                             int* __restrict__ actList, int* __restrict__ inactList,
                             int* __restrict__ counts) {
    const int b = blockIdx.x;
    const int lane = threadIdx.x;           // blockDim = 64 (one wave)
    int nA = 0, nI = 0;
    for (int base = 0; base < NN; base += 64) {
        int i = base + lane;
        bool act = (i < NP) ? (p_mask[b * NP + i] > 0.0f) : true;
        unsigned long long mAct = __ballot(act);
        unsigned long long below = (1ull << lane) - 1ull;
        int pa = __popcll(mAct & below);
        int pi = __popcll((~mAct) & below);
        if (act) actList[b * NN + nA + pa] = i;
        else     inactList[b * NN + nI + pi] = i;
        int ca = __popcll(mAct);
        nA += ca;
        nI += 64 - ca;
    }
    if (lane == 0) { counts[b * 2] = nA; counts[b * 2 + 1] = nI; }
}

// ---------------------------------------------------------------- W split: fp32 -> bf16 hi/lo
__global__ __launch_bounds__(256) void split_w(const float* __restrict__ W,
                                               unsigned short* __restrict__ hi,
                                               unsigned short* __restrict__ lo) {
    size_t i = ((size_t)blockIdx.x * 256 + threadIdx.x) * 4;
    float4 v = *(const float4*)(W + i);
    unsigned short h0 = f2bf(v.x), h1 = f2bf(v.y), h2 = f2bf(v.z), h3 = f2bf(v.w);
    unsigned short l0 = f2bf(v.x - bf2f(h0)), l1 = f2bf(v.y - bf2f(h1));
    unsigned short l2 = f2bf(v.z - bf2f(h2)), l3 = f2bf(v.w - bf2f(h3));
    uint2 hw, lw;
    hw.x = (unsigned)h0 | ((unsigned)h1 << 16); hw.y = (unsigned)h2 | ((unsigned)h3 << 16);
    lw.x = (unsigned)l0 | ((unsigned)l1 << 16); lw.y = (unsigned)l2 | ((unsigned)l3 << 16);
    *(uint2*)(hi + i) = hw;
    *(uint2*)(lo + i) = lw;
}

// ---------------------------------------------------------------- qk = feat @ W^T (MFMA, split-bf16)
#define LDK 40
__global__ __launch_bounds__(256, 2) void gemm_qk_mfma(
    const float* __restrict__ feature, const float* __restrict__ c_node,
    const float* __restrict__ feat1, const unsigned short* __restrict__ Whi,
    const unsigned short* __restrict__ Wlo, float* __restrict__ qkOut,
    const int layer) {
    const int nt = blockIdx.x;   // 0..5   e-tile
    const int mt = blockIdx.y;   // 0..15  n-tile
    const int gb = blockIdx.z;   // g*4+b
    const int g = gb >> 2, b = gb & 3;
    const int t = threadIdx.x;

    __shared__ unsigned short Ahi[128][LDK], Alo[128][LDK];
    __shared__ unsigned short Bhi[128][LDK], Blo[128][LDK];

    const int srow = t >> 1;
    const int skq = (t & 1) * 16;
    const float* Arow;
    if (layer == 0) {
        int grow = mt * 128 + srow;
        Arow = (grow < NP) ? feature + ((size_t)b * NP + grow) * DD
                           : c_node + (size_t)b * DD;
    } else {
        Arow = feat1 + ((size_t)gb * NN + mt * 128 + srow) * DD;
    }
    const unsigned short* BrowH = Whi + ((size_t)g * DD + nt * 128 + srow) * DD;
    const unsigned short* BrowL = Wlo + ((size_t)g * DD + nt * 128 + srow) * DD;

    const int wv = t >> 6, lane = t & 63;
    const int wr = wv >> 1, wc = wv & 1;
    const int fr = lane & 15, kg = lane >> 4;

    f32x4 acc[4][4] = {};

    for (int k0 = 0; k0 < DD; k0 += 32) {
        float af[16];
        *(float4*)(af + 0)  = *(const float4*)(Arow + k0 + skq + 0);
        *(float4*)(af + 4)  = *(const float4*)(Arow + k0 + skq + 4);
        *(float4*)(af + 8)  = *(const float4*)(Arow + k0 + skq + 8);
        *(float4*)(af + 12) = *(const float4*)(Arow + k0 + skq + 12);
        uint4 bh0 = *(const uint4*)(BrowH + k0 + skq);
        uint4 bh1 = *(const uint4*)(BrowH + k0 + skq + 8);
        uint4 bl0 = *(const uint4*)(BrowL + k0 + skq);
        uint4 bl1 = *(const uint4*)(BrowL + k0 + skq + 8);

        __syncthreads();

        unsigned int hiw[8], low[8];
#pragma unroll
        for (int p = 0; p < 8; p++) {
            float x0 = af[2 * p], x1 = af[2 * p + 1];
            unsigned short h0 = f2bf(x0), h1 = f2bf(x1);
            unsigned short l0 = f2bf(x0 - bf2f(h0)), l1 = f2bf(x1 - bf2f(h1));
            hiw[p] = (unsigned)h0 | ((unsigned)h1 << 16);
            low[p] = (unsigned)l0 | ((unsigned)l1 << 16);
        }
        *(uint4*)&Ahi[srow][skq + 0] = make_uint4(hiw[0], hiw[1], hiw[2], hiw[3]);
        *(uint4*)&Ahi[srow][skq + 8] = make_uint4(hiw[4], hiw[5], hiw[6], hiw[7]);
        *(uint4*)&Alo[srow][skq + 0] = make_uint4(low[0], low[1], low[2], low[3]);
        *(uint4*)&Alo[srow][skq + 8] = make_uint4(low[4], low[5], low[6], low[7]);
        *(uint4*)&Bhi[srow][skq + 0] = bh0;
        *(uint4*)&Bhi[srow][skq + 8] = bh1;
        *(uint4*)&Blo[srow][skq + 0] = bl0;
        *(uint4*)&Blo[srow][skq + 8] = bl1;

        __syncthreads();

        bf16x8 bh[4], bl[4];
#pragma unroll
        for (int j = 0; j < 4; j++) {
            int row = wc * 64 + j * 16 + fr;
            bh[j] = *(const bf16x8*)&Bhi[row][kg * 8];
            bl[j] = *(const bf16x8*)&Blo[row][kg * 8];
        }
#pragma unroll
        for (int i = 0; i < 4; i++) {
            int row = wr * 64 + i * 16 + fr;
            bf16x8 ah = *(const bf16x8*)&Ahi[row][kg * 8];
            bf16x8 al = *(const bf16x8*)&Alo[row][kg * 8];
#pragma unroll
            for (int j = 0; j < 4; j++) {
                acc[i][j] = __builtin_amdgcn_mfma_f32_16x16x32_bf16(ah, bh[j], acc[i][j], 0, 0, 0);
                acc[i][j] = __builtin_amdgcn_mfma_f32_16x16x32_bf16(ah, bl[j], acc[i][j], 0, 0, 0);
                acc[i][j] = __builtin_amdgcn_mfma_f32_16x16x32_bf16(al, bh[j], acc[i][j], 0, 0, 0);
            }
        }
    }

    float* outB = qkOut + (size_t)gb * NN * DD;
#pragma unroll
    for (int i = 0; i < 4; i++) {
#pragma unroll
        for (int j = 0; j < 4; j++) {
            int rbase = mt * 128 + wr * 64 + i * 16 + kg * 4;
            int cbase = nt * 128 + wc * 64 + j * 16 + fr;
#pragma unroll
            for (int r = 0; r < 4; r++)
                outB[(size_t)(rbase + r) * DD + cbase] = acc[i][j][r];
        }
    }
}

// ---------------------------------------------------------------- sq, sk per row
__global__ __launch_bounds__(256) void sqsk(
    const float* __restrict__ qk, const float* __restrict__ attn_w,
    float* __restrict__ sq, float* __restrict__ sk) {
    const int gb = blockIdx.y, g = gb >> 2;
    const int w = threadIdx.x >> 6, lane = threadIdx.x & 63;
    const int n = blockIdx.x * 4 + w;
    const float* row = qk + ((size_t)gb * NN + n) * DD;
    const float* aw = attn_w + (size_t)g * HH * 2 * DHH;
#pragma unroll
    for (int h = 0; h < HH; h++) {
        float2 v = *(const float2*)(row + h * DHH + lane * 2);
        float q = v.x * aw[h * 256 + lane * 2] + v.y * aw[h * 256 + lane * 2 + 1];
        float k2 = v.x * aw[h * 256 + 128 + lane * 2] + v.y * aw[h * 256 + 128 + lane * 2 + 1];
        q = waveReduce(q);
        k2 = waveReduce(k2);
        if (lane == 0) {
            sq[((size_t)gb * NN + n) * HH + h] = q;
            sk[((size_t)gb * NN + n) * HH + h] = k2;
        }
    }
}

// ---------------------------------------------------------------- column sums of qk
__global__ __launch_bounds__(256) void colsum_part(const float* __restrict__ qk,
                                                   float* __restrict__ S_part) {
    const int gb = blockIdx.y;
    const int d = blockIdx.x * 256 + threadIdx.x;
    const int ch = blockIdx.z;
    const float* p = qk + ((size_t)gb * NN + (size_t)ch * 256) * DD + d;
    float s0 = 0, s1 = 0, s2 = 0, s3 = 0;
    for (int n = 0; n < 256; n += 4) {
        s0 += p[0];
        s1 += p[(size_t)DD];
        s2 += p[(size_t)2 * DD];
        s3 += p[(size_t)3 * DD];
        p += (size_t)4 * DD;
    }
    S_part[((size_t)gb * 8 + ch) * DD + d] = ((s0 + s1) + (s2 + s3));
}

__global__ __launch_bounds__(256) void finishS(const float* __restrict__ S_part,
                                               float* __restrict__ S_all,
                                               float* __restrict__ hidU) {
    const int gb = blockIdx.y;
    const int d = blockIdx.x * 256 + threadIdx.x;
    float s = 0;
#pragma unroll
    for (int c = 0; c < 8; c++) s += S_part[((size_t)gb * 8 + c) * DD + d];
    S_all[(size_t)gb * DD + d] = s;
    hidU[(size_t)gb * DD + d] = fast_tanh(s * (1.0f / 2048.0f));
}

// ---------------------------------------------------------------- masked-q rows (layer 1)
__global__ __launch_bounds__(256) void update_inactive(
    const float* __restrict__ feature, const float* __restrict__ c_node,
    const float* __restrict__ hidU, const int* __restrict__ inactList,
    const int* __restrict__ counts, float* __restrict__ feat1) {
    const int gb = blockIdx.y, b = gb & 3;
    const int idx = blockIdx.x;
    if (idx >= counts[b * 2 + 1]) return;
    const int n = inactList[b * NN + idx];
    const float* src = (n < NP) ? feature + ((size_t)b * NP + n) * DD
                                : c_node + (size_t)b * DD;
    const float* hu = hidU + (size_t)gb * DD;
    float* dst = feat1 + ((size_t)gb * NN + n) * DD;
    for (int d = threadIdx.x; d < DD; d += 256) dst[d] = src[d] + hu[d];
}

// ---------------------------------------------------------------- qk -> qkT (bf16, active-compacted, transposed)
__global__ __launch_bounds__(256) void transpose_compact(
    const float* __restrict__ qk, const int* __restrict__ actList,
    const int* __restrict__ counts, unsigned short* __restrict__ qkT) {
    const int gb = blockIdx.z, b = gb & 3;
    const int h = blockIdx.y;
    const int jt = blockIdx.x;
    const int nAct = counts[b * 2];
    if (jt * 64 >= nAct) return;

    __shared__ unsigned short T[64][130];
    const int t = threadIdx.x;
    const int jr = t >> 2, dseg = t & 3;
    int jj = jt * 64 + jr;
    int kn = actList[b * NN + (jj < nAct ? jj : nAct - 1)];
    const float* srow = qk + ((size_t)gb * NN + kn) * DD + h * DHH + dseg * 32;
#pragma unroll
    for (int i = 0; i < 8; i++) {
        float4 v = *(const float4*)(srow + i * 4);
        int d = dseg * 32 + i * 4;
        unsigned int w0 = (unsigned)f2bf(v.x) | ((unsigned)f2bf(v.y) << 16);
        unsigned int w1 = (unsigned)f2bf(v.z) | ((unsigned)f2bf(v.w) << 16);
        *(unsigned int*)&T[jr][d] = w0;
        *(unsigned int*)&T[jr][d + 2] = w1;
    }
    __syncthreads();
    const int dd = t >> 1, jh = t & 1;
    unsigned short* orow = qkT + ((size_t)gb * DD + h * DHH + dd) * NN + jt * 64 + jh * 32;
#pragma unroll
    for (int i = 0; i < 4; i++) {
        unsigned short vs[8];
#pragma unroll
        for (int j2 = 0; j2 < 8; j2++) vs[j2] = T[jh * 32 + i * 8 + j2][dd];
        uint4 o;
        o.x = (unsigned)vs[0] | ((unsigned)vs[1] << 16);
        o.y = (unsigned)vs[2] | ((unsigned)vs[3] << 16);
        o.z = (unsigned)vs[4] | ((unsigned)vs[5] << 16);
        o.w = (unsigned)vs[6] | ((unsigned)vs[7] << 16);
        *(uint4*)(orow + i * 8) = o;
    }
}

// ---------------------------------------------------------------- active-q attention (layer 1, MFMA)
__global__ __launch_bounds__(256) void attn_active_mfma(
    const unsigned short* __restrict__ qkT, const float* __restrict__ sq,
    const float* __restrict__ sk, const float* __restrict__ S_all,
    const float* __restrict__ feature, const float* __restrict__ c_node,
    const int* __restrict__ actList, const int* __restrict__ counts,
    float* __restrict__ feat1) {
    const int fid = blockIdx.x + 32 * (blockIdx.y + 6 * blockIdx.z);
    const int nfid = (fid & 7) * 384 + (fid >> 3);
    const int qt = nfid & 31;
    const int hg = nfid >> 5;
    const int h = hg % 6;
    const int gb = hg / 6;
    const int b = gb & 3;
    const int nAct = counts[b * 2];
    if (qt * 64 >= nAct) return;

    __shared__ unsigned short Vt[128][128];
    __shared__ float Ek_s[128];
    __shared__ float Eq_s[64];
    __shared__ int qIdx[64];

    const int t = threadIdx.x;
    const int wv = t >> 6, lane = t & 63;
    const int fr = lane & 15, kg = lane >> 4;
    const int myq = wv * 16 + fr;

    if (t < 64) {
        int jj = qt * 64 + t;
        int qn = actList[b * NN + (jj < nAct ? jj : nAct - 1)];
        qIdx[t] = (jj < nAct) ? qn : -1;
        Eq_s[t] = __expf(2.0f * sq[((size_t)gb * NN + qn) * HH + h]);
    }

    const int sd = t >> 1, sh = t & 1;
    const unsigned short* Trow = qkT + ((size_t)gb * DD + h * DHH + sd) * NN;

    f32x4 acc[8] = {};
    float dsum = 0.0f;
    const int nTiles = (nAct + 127) >> 7;

    for (int kt = 0; kt < nTiles; kt++) {
        uint4 vld[8];
        const unsigned short* src = Trow + kt * 128 + sh * 64;
#pragma unroll
        for (int i = 0; i < 8; i++) vld[i] = *(const uint4*)(src + i * 8);
        float ekv = 0.0f;
        if (t < 128) {
            int jk = kt * 128 + t;
            int kn2 = actList[b * NN + (jk < nAct ? jk : nAct - 1)];
            ekv = __expf(2.0f * sk[((size_t)gb * NN + kn2) * HH + h]);
        }
        __syncthreads();
#pragma unroll
        for (int i = 0; i < 8; i++) {
            int cs = (sh * 8 + i) ^ (sd & 15);
            *(uint4*)&Vt[sd][cs * 8] = vld[i];
        }
        if (t < 128) Ek_s[t] = ekv;
        __syncthreads();

        const float myEq = Eq_s[myq];
        bf16x8 ef[4];
#pragma unroll
        for (int ksub = 0; ksub < 4; ksub++) {
            union { unsigned int u[4]; bf16x8 v; } pk;
#pragma unroll
            for (int jp = 0; jp < 4; jp++) {
                unsigned short e2[2];
#pragma unroll
                for (int q2 = 0; q2 < 2; q2++) {
                    int kl = ksub * 32 + kg * 8 + jp * 2 + q2;
                    float z = myEq * Ek_s[kl];
                    float r = __builtin_amdgcn_rcpf(1.0f + z);
                    float th = 1.0f - 2.0f * r;
                    float e = __expf(th) - 1.0f;
                    e = (kt * 128 + kl < nAct) ? e : 0.0f;
                    dsum += e;
                    e2[q2] = f2bf(e);
                }
                pk.u[jp] = (unsigned)e2[0] | ((unsigned)e2[1] << 16);
            }
            ef[ksub] = pk.v;
        }

#pragma unroll
        for (int dt = 0; dt < 8; dt++) {
            int d = dt * 16 + fr;
#pragma unroll
            for (int ksub = 0; ksub < 4; ksub++) {
                int cs = (ksub * 4 + kg) ^ fr;
                bf16x8 va = *(const bf16x8*)&Vt[d][cs * 8];
                acc[dt] = __builtin_amdgcn_mfma_f32_16x16x32_bf16(va, ef[ksub], acc[dt], 0, 0, 0);
            }
        }
    }

    dsum += __shfl_xor(dsum, 16);
    dsum += __shfl_xor(dsum, 32);
    const float rden = 1.0f / (2048.0f + dsum);

    const int qn = qIdx[myq];
    if (qn >= 0) {
        const float* res = (qn < NP) ? feature + ((size_t)b * NP + qn) * DD + h * DHH
                                     : c_node + (size_t)b * DD + h * DHH;
        float* dst = feat1 + ((size_t)gb * NN + qn) * DD + h * DHH;
        const float* Sp = S_all + (size_t)gb * DD + h * DHH;
#pragma unroll
        for (int dt = 0; dt < 8; dt++) {
            int d0 = dt * 16 + kg * 4;
            float4 sv = *(const float4*)(Sp + d0);
            float4 rv = *(const float4*)(res + d0);
            float4 o;
            o.x = rv.x + fast_tanh((acc[dt][0] + sv.x) * rden);
            o.y = rv.y + fast_tanh((acc[dt][1] + sv.y) * rden);
            o.z = rv.z + fast_tanh((acc[dt][2] + sv.z) * rden);
            o.w = rv.w + fast_tanh((acc[dt][3] + sv.w) * rden);
            *(float4*)(dst + d0) = o;
        }
    }
}

// ---------------------------------------------------------------- layer-2 attention, q = N-1 only
// Two-phase: (1) j-parallel e into LDS (+k cache), (2) independent-address
// weighted sum, unroll-4 so loads pipeline.
__global__ __launch_bounds__(256) void attn_final(
    const float* __restrict__ qk, const float* __restrict__ sq,
    const float* __restrict__ sk, const float* __restrict__ S_all,
    const float* __restrict__ feat1, const int* __restrict__ actList,
    const int* __restrict__ counts, float* __restrict__ gout) {
    const int h = blockIdx.x;
    const int gb = blockIdx.y, b = gb & 3;
    const int t = threadIdx.x;
    const int nAct = counts[b * 2];

    __shared__ float e_s[NN];        // 8 KB
    __shared__ int   k_s[NN];        // 8 KB
    __shared__ float wsum_s[4];
    __shared__ float acc_s[128];

    const float Eq = __expf(2.0f * sq[((size_t)gb * NN + (NN - 1)) * HH + h]);

    // phase 1: e_j, j-parallel (transcendentals fully parallel across threads)
    float wpart = 0.0f;
    for (int j = t; j < nAct; j += 256) {
        int k = actList[b * NN + j];
        float Ek = __expf(2.0f * sk[((size_t)gb * NN + k) * HH + h]);
        float z = Eq * Ek;
        float th = 1.0f - 2.0f * __builtin_amdgcn_rcpf(1.0f + z);
        float e = __expf(th) - 1.0f;
        e_s[j] = e;
        k_s[j] = k;
        wpart += e;
    }
    wpart = waveReduce(wpart);
    if ((t & 63) == 0) wsum_s[t >> 6] = wpart;
    __syncthreads();
    const float wsum = wsum_s[0] + wsum_s[1] + wsum_s[2] + wsum_s[3];

    // phase 2: acc[d] = sum_j e_s[j] * qk[k_j][h*128+d]; addresses from LDS ->
    // independent global loads, pipeline with unroll.
    const int d = t & 127, seg = t >> 7;     // 2 j-segments
    const float* qbase = qk + (size_t)gb * NN * DD + h * DHH + d;
    float acc = 0.0f;
#pragma unroll 4
    for (int j = seg; j < nAct; j += 2) {
        acc = fmaf(e_s[j], qbase[(size_t)k_s[j] * DD], acc);
    }
    if (seg == 0) acc_s[d] = acc;
    __syncthreads();
    if (seg == 1) acc_s[d] += acc;
    __syncthreads();

    if (t < 128) {
        float numer = acc_s[t] + S_all[(size_t)gb * DD + h * DHH + t];
        float hid = fast_tanh(numer / (2048.0f + wsum));
        gout[(size_t)gb * DD + h * DHH + t] =
            feat1[((size_t)gb * NN + (NN - 1)) * DD + h * DHH + t] + hid;
    }
}

// ---------------------------------------------------------------- MLP: grid-parallel GEMV
__global__ __launch_bounds__(256) void mlp_gemv(
    const float* __restrict__ xin, const float* __restrict__ w,
    const float* __restrict__ bias, float* __restrict__ yout) {
    const int gb = blockIdx.y;
    const int wv = threadIdx.x >> 6, lane = threadIdx.x & 63;
    const int f = blockIdx.x * 4 + wv;
    const float* row = w + (size_t)f * FHH;
    const float* x = xin + (size_t)gb * FHH;
    float s = 0.0f;
#pragma unroll
    for (int d = lane * 4; d < FHH; d += 256) {
        float4 rv = *(const float4*)(row + d);
        float4 xv = *(const float4*)(x + d);
        s += rv.x * xv.x + rv.y * xv.y + rv.z * xv.z + rv.w * xv.w;
    }
    s = waveReduce(s);
    if (lane == 0) yout[(size_t)gb * FHH + f] = fmaxf(s + bias[f], 0.0f);
}

__global__ __launch_bounds__(256) void fc_out(
    const float* __restrict__ x2, const float* __restrict__ fcw,
    const float* __restrict__ fcb, float* __restrict__ out) {
    const int gb = blockIdx.x, g = gb >> 2, b = gb & 3;
    const int wv = threadIdx.x >> 6, lane = threadIdx.x & 63;
    const float* row = fcw + ((size_t)g * NCC + wv) * FHH;
    const float* x = x2 + (size_t)gb * FHH;
    float s = 0.0f;
#pragma unroll
    for (int d = lane * 4; d < FHH; d += 256) {
        float4 rv = *(const float4*)(row + d);
        float4 xv = *(const float4*)(x + d);
        s += rv.x * xv.x + rv.y * xv.y + rv.z * xv.z + rv.w * xv.w;
    }
    s = waveReduce(s);
    if (lane == 0) out[g * (BB * NCC) + b * NCC + wv] = s + fcb[g * NCC + wv];
}

extern "C" void kernel_launch(void* const* d_in, const int* in_sizes, int n_in,
                              void* d_out, int out_size, void* d_ws, size_t ws_size,
                              hipStream_t stream) {
    const float* p_mask  = (const float*)d_in[0];
    const float* feature = (const float*)d_in[1];
    const float* c_node  = (const float*)d_in[2];
    const float* W_gat   = (const float*)d_in[3];
    const float* attn_w  = (const float*)d_in[4];
    const float* w0      = (const float*)d_in[5];
    const float* b0      = (const float*)d_in[6];
    const float* w1      = (const float*)d_in[7];
    const float* b1      = (const float*)d_in[8];
    const float* fcw     = (const float*)d_in[9];
    const float* fcb     = (const float*)d_in[10];
    float* out = (float*)d_out;

    // workspace carve-up (~263 MB)
    float* fw = (float*)d_ws;
    size_t off = 0;
    float* feat1  = fw + off; off += (size_t)16 * NN * DD;
    float* qk     = fw + off; off += (size_t)16 * NN * DD;
    float* sq     = fw + off; off += (size_t)16 * NN * HH;
    float* sk     = fw + off; off += (size_t)16 * NN * HH;
    float* S_part = fw + off; off += (size_t)16 * 8 * DD;
    float* S_all  = fw + off; off += (size_t)16 * DD;
    float* hidU   = fw + off; off += (size_t)16 * DD;
    float* gout   = fw + off; off += (size_t)16 * DD;
    float* x1     = fw + off; off += (size_t)16 * FHH;
    float* x2     = fw + off; off += (size_t)16 * FHH;
    int* actList   = (int*)(fw + off); off += (size_t)BB * NN;
    int* inactList = (int*)(fw + off); off += (size_t)BB * NN;
    int* counts    = (int*)(fw + off); off += 16;
    unsigned short* Whi = (unsigned short*)(fw + off); off += (size_t)4 * DD * DD / 2;
    unsigned short* Wlo = (unsigned short*)(fw + off); off += (size_t)4 * DD * DD / 2;
    unsigned short* qkT = (unsigned short*)(fw + off); off += (size_t)16 * DD * NN / 2;

    mask_compact<<<dim3(BB), dim3(64), 0, stream>>>(p_mask, actList, inactList, counts);
    split_w<<<dim3(4 * DD * DD / 1024), dim3(256), 0, stream>>>(W_gat, Whi, Wlo);

    // -------- layer 1
    gemm_qk_mfma<<<dim3(6, 16, 16), dim3(256), 0, stream>>>(feature, c_node, feat1,
                                                            Whi, Wlo, qk, 0);
    sqsk<<<dim3(NN / 4, 16), dim3(256), 0, stream>>>(qk, attn_w, sq, sk);
    colsum_part<<<dim3(3, 16, 8), dim3(256), 0, stream>>>(qk, S_part);
    finishS<<<dim3(3, 16), dim3(256), 0, stream>>>(S_part, S_all, hidU);
    update_inactive<<<dim3(NN, 16), dim3(256), 0, stream>>>(feature, c_node, hidU,
                                                            inactList, counts, feat1);
    transpose_compact<<<dim3(32, HH, 16), dim3(256), 0, stream>>>(qk, actList, counts, qkT);
    attn_active_mfma<<<dim3(32, HH, 16), dim3(256), 0, stream>>>(qkT, sq, sk, S_all,
                                                                 feature, c_node,
                                                                 actList, counts, feat1);

    // -------- layer 2 (attention only needed for q = N-1)
    gemm_qk_mfma<<<dim3(6, 16, 16), dim3(256), 0, stream>>>(feature, c_node, feat1,
                                                            Whi, Wlo, qk, 1);
    sqsk<<<dim3(NN / 4, 16), dim3(256), 0, stream>>>(qk, attn_w, sq, sk);
    colsum_part<<<dim3(3, 16, 8), dim3(256), 0, stream>>>(qk, S_part);
    finishS<<<dim3(3, 16), dim3(256), 0, stream>>>(S_part, S_all, hidU);
    attn_final<<<dim3(HH, 16), dim3(256), 0, stream>>>(qk, sq, sk, S_all, feat1,
                                                       actList, counts, gout);

    // -------- MLP head (grid-parallel)
    mlp_gemv<<<dim3(FHH / 4, 16), dim3(256), 0, stream>>>(gout, w0, b0, x1);
    mlp_gemv<<<dim3(FHH / 4, 16), dim3(256), 0, stream>>>(x1, w1, b1, x2);
    fc_out<<<dim3(16), dim3(256), 0, stream>>>(x2, fcw, fcb, out);
}